// Round 4
// baseline (765.994 us; speedup 1.0000x reference)
//
#include <hip/hip_runtime.h>

// LinearAttention on MI355X (gfx950), bf16 MFMA pipeline.
// R5: one-phase READ-AHEAD pipeline in gemm256. Each phase issues the ds_reads
// for the NEXT phase's MFMA cluster (P1->b23(t), P2->aG(t), P3->aF(t+1),
// P4->b01(t+1)+stage(t+2)), so the LDS port services reads while MFMAs run.
// Register sets need no double-buffering (each set's re-read is after its last
// use). Tile boundary = vmcnt(0) at end of P2 draining >=2.5-phase-old stage
// loads. sched_barrier(0) pins MFMA clusters inside their phase (rule #18).
// GEMM2/2b keep the 128^2 kernel.

#define EPS 1e-6f

using u16 = unsigned short;
typedef __attribute__((ext_vector_type(4))) float f32x4;
typedef __attribute__((ext_vector_type(8))) __bf16 bf16x8;

__device__ __forceinline__ u16 f2b(float f) {
  unsigned u = __builtin_bit_cast(unsigned, f);
  u += 0x7FFFu + ((u >> 16) & 1u);     // RNE
  return (u16)(u >> 16);
}
__device__ __forceinline__ float b2f(u16 h) {
  return __builtin_bit_cast(float, (unsigned)h << 16);
}

typedef const __attribute__((address_space(1))) void* gas1_t;
typedef __attribute__((address_space(3))) void* las3_t;

__device__ __forceinline__ void load16_to_lds(const void* g, void* l) {
  __builtin_amdgcn_global_load_lds((gas1_t)g, (las3_t)l, 16, 0, 0);
}

#define BARRIER() do { asm volatile("" ::: "memory"); __builtin_amdgcn_s_barrier(); asm volatile("" ::: "memory"); } while (0)
#define SCHED0()  __builtin_amdgcn_sched_barrier(0)
#define WAITV(n)  asm volatile("s_waitcnt vmcnt(" #n ")" ::: "memory")
#define MFMA16(a, b, c) __builtin_amdgcn_mfma_f32_16x16x32_bf16((a), (b), (c), 0, 0, 0)

// Stage one 128x64 half-tile: LDS dest linear (global_load_lds requirement),
// global source column pre-swizzled with the involution chunk ^= (row&7) so the
// swizzled ds_read side reads the right bytes (rule: both-sides-or-neither).
__device__ __forceinline__ void stage_half(const u16* g, int ld, u16* l,
                                           int r0, int csw, int woff) {
  load16_to_lds(g + (long long)r0 * ld + csw, l + woff);
  load16_to_lds(g + (long long)(r0 + 64) * ld + csw, l + 4096 + woff);
}

// ---------------------------------------------------------------------------
// 256x256-tile, BK=64, 8 waves (2M x 4N), double-buffered 128 KiB LDS.
// 4 phases per K-tile; each phase ISSUES the ds_reads consumed by the NEXT
// phase's MFMA cluster (one-phase look-ahead), so LDS reads overlap MFMA.
// Phase p: [issue reads/stages] barrier [auto-counted lgkm wait] MFMA barrier.
// Boundary vmcnt(0) at end of P2 confirms tile t+1 staged (loads are >=2.5
// phases old there -> near-free).
// MODE 0: GEMM1 fused epilogue (q n-major relu+eps / kT,vT transposed / ksum).
// MODE 1: bf16 out.  MODE 2: f32 out, v*z[row] + bias[col].
// Requires M%256==0, N%256==0, K%64==0, (gridDim.x*gridDim.y)%8==0.
// ---------------------------------------------------------------------------
template<int MODE>
__global__ __launch_bounds__(512, 2) void gemm256(
    const u16* __restrict__ A, const u16* __restrict__ B, void* __restrict__ Cv,
    int M, int N, int K, int lda, int ldb, int ldc,
    long long sA, long long sB, long long sC,
    const float* __restrict__ zvec, const float* __restrict__ bias,
    u16* __restrict__ kT, u16* __restrict__ vT, float* __restrict__ ksum)
{
  __shared__ __align__(16) u16 shA[32768];   // [2 buf][2 half][128 r][8 chunks*8]
  __shared__ __align__(16) u16 shB[32768];

  const int tid  = threadIdx.x;
  const int lane = tid & 63, wave = tid >> 6;
  const int wr = wave >> 2, wc = wave & 3;           // 2M x 4N wave grid
  const int quad = lane >> 4, lc = lane & 15;

  // XCD-aware swizzle (bijective: grid multiple of 8)
  const int TN = gridDim.y;
  const int lin = blockIdx.x + gridDim.x * blockIdx.y;
  const int xcd = lin & 7, g = lin >> 3;
  const int bm = (g / TN) * 8 + xcd;
  const int bn = g % TN;
  const int bz = blockIdx.z;
  const u16* Ab = A + (long long)bz * sA;
  const u16* Bb = B + (long long)bz * sB;

  // staging addressing: thread covers chunks {tid, 512+tid} of each half-tile
  const int r0   = tid >> 3;                                   // rows 0..63 (+64)
  const int csw  = (((tid & 7) ^ ((tid >> 3) & 7)) << 3);      // inverse-swz col
  const int woff = wave * 512;                                 // wave-uniform LDS off

  // fragment read addressing (swizzled chunk index, constant per lane)
  const int ch0 = ((quad ^ (lane & 7)) << 3);                  // ksub 0
  const int ch1 = (((4 + quad) ^ (lane & 7)) << 3);            // ksub 1
  const int aRow = wr * 128 + lc;
  const int bRow = wc * 64 + lc;

  const int NT = K >> 6;

  f32x4 acc[8][4];
  #pragma unroll
  for (int i = 0; i < 8; ++i)
    #pragma unroll
    for (int j = 0; j < 4; ++j) acc[i][j] = f32x4{0.f, 0.f, 0.f, 0.f};

  auto stA = [&](int h, int t) {
    stage_half(Ab + ((long long)bm * 256 + h * 128) * lda + t * 64, lda,
               shA + (t & 1) * 16384 + h * 8192, r0, csw, woff);
  };
  auto stB = [&](int h, int t) {
    stage_half(Bb + ((long long)bn * 256 + h * 128) * ldb + t * 64, ldb,
               shB + (t & 1) * 16384 + h * 8192, r0, csw, woff);
  };
  auto stAll = [&](int t) { stA(0, t); stA(1, t); stB(0, t); stB(1, t); };

  bf16x8 aF[4][2], aG[4][2], b01[2][2], b23[2][2];

  // prologue: stage tile0 + tile1; wait tile0 (vmcnt(8) leaves tile1 flying)
  stAll(0);
  if (NT > 1) { stAll(1); WAITV(8); }
  else        { WAITV(0); }
  BARRIER();
  // pre-read P1(0)'s operands: aF(0), b01(0)
  #pragma unroll
  for (int i = 0; i < 4; ++i) {
    aF[i][0] = *(const bf16x8*)&shA[(aRow + i * 16) * 64 + ch0];
    aF[i][1] = *(const bf16x8*)&shA[(aRow + i * 16) * 64 + ch1];
  }
  #pragma unroll
  for (int j = 0; j < 2; ++j) {
    b01[j][0] = *(const bf16x8*)&shB[(bRow + j * 16) * 64 + ch0];
    b01[j][1] = *(const bf16x8*)&shB[(bRow + j * 16) * 64 + ch1];
  }

  for (int t = 0; t < NT; ++t) {
    const u16* aB = shA + (t & 1) * 16384;
    const u16* bB = shB + (t & 1) * 16384;
    const u16* aN = shA + ((t + 1) & 1) * 16384;   // next tile's buffers
    const u16* bN = shB + ((t + 1) & 1) * 16384;
    const bool rdn = (t + 1 < NT);

    // ---- P1: issue b23(t) [for P2]; MFMA aF(t) x b01(t)
    #pragma unroll
    for (int j = 0; j < 2; ++j) {
      b23[j][0] = *(const bf16x8*)&bB[(bRow + (2 + j) * 16) * 64 + ch0];
      b23[j][1] = *(const bf16x8*)&bB[(bRow + (2 + j) * 16) * 64 + ch1];
    }
    BARRIER(); SCHED0();
    __builtin_amdgcn_s_setprio(1);
    #pragma unroll
    for (int i = 0; i < 4; ++i)
      #pragma unroll
      for (int j = 0; j < 2; ++j) {
        acc[i][j] = MFMA16(aF[i][0], b01[j][0], acc[i][j]);
        acc[i][j] = MFMA16(aF[i][1], b01[j][1], acc[i][j]);
      }
    __builtin_amdgcn_s_setprio(0);
    SCHED0(); BARRIER();

    // ---- P2: issue aG(t) [for P3]; MFMA aF(t) x b23(t); boundary vmcnt
    #pragma unroll
    for (int i = 0; i < 4; ++i) {
      aG[i][0] = *(const bf16x8*)&aB[(aRow + (4 + i) * 16) * 64 + ch0];
      aG[i][1] = *(const bf16x8*)&aB[(aRow + (4 + i) * 16) * 64 + ch1];
    }
    BARRIER(); SCHED0();
    __builtin_amdgcn_s_setprio(1);
    #pragma unroll
    for (int i = 0; i < 4; ++i)
      #pragma unroll
      for (int j = 0; j < 2; ++j) {
        acc[i][2 + j] = MFMA16(aF[i][0], b23[j][0], acc[i][2 + j]);
        acc[i][2 + j] = MFMA16(aF[i][1], b23[j][1], acc[i][2 + j]);
      }
    __builtin_amdgcn_s_setprio(0);
    SCHED0();
    WAITV(0);        // tile t+1 staged (loads issued >=2.5 phases ago)
    BARRIER();

    // ---- P3: issue aF(t+1) [for P1(t+1), other buf]; MFMA aG(t) x b01(t)
    if (rdn) {
      #pragma unroll
      for (int i = 0; i < 4; ++i) {
        aF[i][0] = *(const bf16x8*)&aN[(aRow + i * 16) * 64 + ch0];
        aF[i][1] = *(const bf16x8*)&aN[(aRow + i * 16) * 64 + ch1];
      }
    }
    BARRIER(); SCHED0();
    __builtin_amdgcn_s_setprio(1);
    #pragma unroll
    for (int i = 0; i < 4; ++i)
      #pragma unroll
      for (int j = 0; j < 2; ++j) {
        acc[4 + i][j] = MFMA16(aG[i][0], b01[j][0], acc[4 + i][j]);
        acc[4 + i][j] = MFMA16(aG[i][1], b01[j][1], acc[4 + i][j]);
      }
    __builtin_amdgcn_s_setprio(0);
    SCHED0(); BARRIER();

    // ---- P4: stage tile t+2 (current buf, now dead); issue b01(t+1);
    //          MFMA aG(t) x b23(t)
    if (t + 2 < NT) stAll(t + 2);
    if (rdn) {
      #pragma unroll
      for (int j = 0; j < 2; ++j) {
        b01[j][0] = *(const bf16x8*)&bN[(bRow + j * 16) * 64 + ch0];
        b01[j][1] = *(const bf16x8*)&bN[(bRow + j * 16) * 64 + ch1];
      }
    }
    BARRIER(); SCHED0();
    __builtin_amdgcn_s_setprio(1);
    #pragma unroll
    for (int i = 0; i < 4; ++i)
      #pragma unroll
      for (int j = 0; j < 2; ++j) {
        acc[4 + i][2 + j] = MFMA16(aG[i][0], b23[j][0], acc[4 + i][2 + j]);
        acc[4 + i][2 + j] = MFMA16(aG[i][1], b23[j][1], acc[4 + i][2 + j]);
      }
    __builtin_amdgcn_s_setprio(0);
    SCHED0(); BARRIER();
  }

  // ---- epilogue.  C/D layout (m89): col = lane&15, row = (lane>>4)*4 + reg
  const long long rowb = (long long)bm * 256 + wr * 128 + quad * 4;
  const int colb = bn * 256 + wc * 64 + lc;

  if (MODE == 0) {
    const int region = colb >> 10;           // 0:q 1:k 2:v (tile stays in-region)
    if (region == 0) {
      u16* q = (u16*)Cv;
      #pragma unroll
      for (int i = 0; i < 8; ++i)
        #pragma unroll
        for (int j = 0; j < 4; ++j) {
          const int col = colb + j * 16;
          #pragma unroll
          for (int r = 0; r < 4; ++r) {
            const long long row = rowb + i * 16 + r;
            q[row * ldc + col] = f2b(fmaxf(acc[i][j][r], 0.f) + EPS);
          }
        }
    } else {
      const bool isk = (region == 1);
      const int b = (int)(rowb >> 12);       // batch (256-row tile within batch)
      u16* dst = (isk ? kT : vT) + (long long)b * 1024 * 4096;
      const int nloc = (int)(rowb & 4095);
      #pragma unroll
      for (int j = 0; j < 4; ++j) {
        const int d = colb + j * 16 - region * 1024;
        float s = 0.f;
        #pragma unroll
        for (int i = 0; i < 8; ++i) {
          ushort4 pk;
          #pragma unroll
          for (int r = 0; r < 4; ++r) {
            float v = acc[i][j][r];
            if (isk) { v = fmaxf(v, 0.f) + EPS; s += v; }
            (&pk.x)[r] = f2b(v);
          }
          *(ushort4*)(dst + (long long)d * 4096 + nloc + i * 16) = pk;
        }
        if (isk) {
          s += __shfl_xor(s, 16);            // reduce 4 quads -> 128 n-rows/wave
          s += __shfl_xor(s, 32);
          if (quad == 0) atomicAdd(&ksum[b * 1024 + d], s);
        }
      }
    }
  } else if (MODE == 2) {
    float* out = (float*)Cv + (long long)bz * sC;
    #pragma unroll
    for (int i = 0; i < 8; ++i)
      #pragma unroll
      for (int j = 0; j < 4; ++j) {
        const int col = colb + j * 16;
        const float bj = bias[col];
        #pragma unroll
        for (int r = 0; r < 4; ++r) {
          const long long row = rowb + i * 16 + r;
          out[row * ldc + col] = acc[i][j][r] * zvec[(long long)bz * M + row] + bj;
        }
      }
  } else {
    u16* out = (u16*)Cv + (long long)bz * sC;
    #pragma unroll
    for (int i = 0; i < 8; ++i)
      #pragma unroll
      for (int j = 0; j < 4; ++j) {
        const int col = colb + j * 16;
        #pragma unroll
        for (int r = 0; r < 4; ++r) {
          const long long row = rowb + i * 16 + r;
          out[row * ldc + col] = f2b(acc[i][j][r]);
        }
      }
  }
}

// ---------------------------------------------------------------------------
// 128^2-tile kernel (m97 structure) — kept for GEMM2/2b whose grids are small.
// C = A * B^T.  MODE 1: bf16 out, plain.
// ---------------------------------------------------------------------------
template<int MODE>
__global__ __launch_bounds__(256) void gemm_abT(
    const u16* __restrict__ A, const u16* __restrict__ B, void* __restrict__ Cv,
    int M, int N, int K, int lda, int ldb, int ldc,
    long long sA, long long sB, long long sC,
    const float* __restrict__ zvec, const float* __restrict__ bias,
    u16* __restrict__ kT, u16* __restrict__ vT, float* __restrict__ ksum)
{
  __shared__ u16 lA[128 * 32];
  __shared__ u16 lB[128 * 32];
  const int tid  = threadIdx.x;
  const int wave = tid >> 6, lane = tid & 63;
  const int TN = gridDim.y;
  const int lin = blockIdx.x + gridDim.x * blockIdx.y;
  const int xcd = lin & 7, g = lin >> 3;
  const int bm = (g / TN) * 8 + xcd;
  const int bn = g % TN;
  const int bz = blockIdx.z;
  const u16* Ab = A + (long long)bz * sA;
  const u16* Bb = B + (long long)bz * sB;

  const int c0 = wave * 64 + lane;
  const int c1 = 256 + c0;
  const u16* gA0 = Ab + (long long)(bm * 128 + (c0 >> 2)) * lda + (c0 & 3) * 8;
  const u16* gA1 = Ab + (long long)(bm * 128 + (c1 >> 2)) * lda + (c1 & 3) * 8;
  const u16* gB0 = Bb + (long long)(bn * 128 + (c0 >> 2)) * ldb + (c0 & 3) * 8;
  const u16* gB1 = Bb + (long long)(bn * 128 + (c1 >> 2)) * ldb + (c1 & 3) * 8;
  u16* lA0 = &lA[(wave * 64) * 8];
  u16* lA1 = &lA[(256 + wave * 64) * 8];
  u16* lB0 = &lB[(wave * 64) * 8];
  u16* lB1 = &lB[(256 + wave * 64) * 8];

  const int wm = (wave & 1) * 64, wn = (wave >> 1) * 64;
  const int aoff = (wm + (lane & 15)) * 32 + (lane >> 4) * 8;
  const int boff = (wn + (lane & 15)) * 32 + (lane >> 4) * 8;

  f32x4 acc[4][4];
  #pragma unroll
  for (int i = 0; i < 4; i++)
    #pragma unroll
    for (int j = 0; j < 4; j++) acc[i][j] = f32x4{0.f, 0.f, 0.f, 0.f};

  for (int k0 = 0; k0 < K; k0 += 32) {
    load16_to_lds(gA0 + k0, lA0);
    load16_to_lds(gA1 + k0, lA1);
    load16_to_lds(gB0 + k0, lB0);
    load16_to_lds(gB1 + k0, lB1);
    __syncthreads();
    bf16x8 af[4], bfv[4];
    #pragma unroll
    for (int i = 0; i < 4; i++) af[i]  = *(const bf16x8*)&lA[aoff + i * 16 * 32];
    #pragma unroll
    for (int j = 0; j < 4; j++) bfv[j] = *(const bf16x8*)&lB[boff + j * 16 * 32];
    #pragma unroll
    for (int i = 0; i < 4; i++)
      #pragma unroll
      for (int j = 0; j < 4; j++)
        acc[i][j] = MFMA16(af[i], bfv[j], acc[i][j]);
    __syncthreads();
  }

  const int quad = lane >> 4, lc = lane & 15;
  const int rowb = bm * 128 + wm + quad * 4;
  const int colb = bn * 128 + wn + lc;

  #pragma unroll
  for (int i = 0; i < 4; i++) {
    #pragma unroll
    for (int j = 0; j < 4; j++) {
      const int col = colb + j * 16;
      float bj = 0.f;
      if (MODE == 2) bj = bias[col];
      #pragma unroll
      for (int r = 0; r < 4; r++) {
        const int row = rowb + i * 16 + r;
        float v = acc[i][j][r];
        if (MODE == 1) {
          ((u16*)Cv + (long long)bz * sC)[(long long)row * ldc + col] = f2b(v);
        } else if (MODE == 2) {
          float zz = zvec[(long long)bz * M + row];
          ((float*)Cv + (long long)bz * sC)[(long long)row * ldc + col] = v * zz + bj;
        }
      }
    }
  }
  (void)kT; (void)vT; (void)ksum;
}

// fp32 -> bf16 bulk convert (vectorized, grid-stride)
__global__ void cvt_f32_bf16(const float* __restrict__ s, u16* __restrict__ d, int n4) {
  int i = blockIdx.x * blockDim.x + threadIdx.x;
  int st = gridDim.x * blockDim.x;
  for (; i < n4; i += st) {
    float4 f = ((const float4*)s)[i];
    uint2 o;
    o.x = (unsigned)f2b(f.x) | ((unsigned)f2b(f.y) << 16);
    o.y = (unsigned)f2b(f.z) | ((unsigned)f2b(f.w) << 16);
    ((uint2*)d)[i] = o;
  }
}

__global__ void zero_f32(float* __restrict__ p, int n) {
  int i = blockIdx.x * blockDim.x + threadIdx.x;
  if (i < n) p[i] = 0.f;
}

// z[row] = 1/(q[row,:]·ksum[b,:] + eps); one wave per row; q is [32768][1024]
__global__ void z_kernel(const u16* __restrict__ qbuf, const float* __restrict__ ksum,
                         float* __restrict__ z) {
  const int row  = blockIdx.x * 4 + (threadIdx.x >> 6);
  const int lane = threadIdx.x & 63;
  const int b = row >> 12;
  const uint4* q = (const uint4*)(qbuf + (long long)row * 1024);
  const float* ks = ksum + b * 1024;
  float s = 0.f;
  #pragma unroll
  for (int c = 0; c < 2; c++) {
    int idx = lane + c * 64;
    uint4 d = q[idx];
    unsigned w[4] = {d.x, d.y, d.z, d.w};
    const float* kk = ks + idx * 8;
    #pragma unroll
    for (int qq = 0; qq < 4; qq++)
      s += b2f((u16)(w[qq] & 0xFFFF)) * kk[qq * 2]
         + b2f((u16)(w[qq] >> 16))    * kk[qq * 2 + 1];
  }
  #pragma unroll
  for (int o = 32; o > 0; o >>= 1) s += __shfl_down(s, o);
  if (lane == 0) z[row] = 1.0f / (s + EPS);
}

extern "C" void kernel_launch(void* const* d_in, const int* in_sizes, int n_in,
                              void* d_out, int out_size, void* d_ws, size_t ws_size,
                              hipStream_t stream) {
  const float* x    = (const float*)d_in[0];   // [8,4096,1024]
  const float* Wqkv = (const float*)d_in[1];   // [3072,1024]
  const float* Wout = (const float*)d_in[2];   // [1024,1024]
  const float* bout = (const float*)d_in[3];   // [1024]

  char* ws = (char*)d_ws;                      // ~310.6 MiB
  u16* x_bf    = (u16*)(ws + 0);               // 64 MiB
  u16* qbuf    = (u16*)(ws + 67108864);        // 64 MiB [32768][1024]
  u16* kT      = (u16*)(ws + 134217728);       // 64 MiB [8][1024][4096]
  u16* vT      = (u16*)(ws + 201326592);       // 64 MiB [8][1024][4096]
  u16* wqkv_bf = (u16*)(ws + 268435456);       // 6 MiB
  u16* wout_bf = (u16*)(ws + 274726912);       // 2 MiB
  u16* kv      = (u16*)(ws + 276824064);       // 16 MiB [8][1024][1024]
  u16* kvwT    = (u16*)(ws + 293601280);       // 16 MiB [8][1024][1024]
  float* ksum  = (float*)(ws + 310378496);     // 32 KiB [8][1024]
  float* z     = (float*)(ws + 310411264);     // 128 KiB [32768]

  cvt_f32_bf16<<<4096, 256, 0, stream>>>(x,    x_bf,    33554432 / 4);
  cvt_f32_bf16<<<1024, 256, 0, stream>>>(Wqkv, wqkv_bf,  3145728 / 4);
  cvt_f32_bf16<<<512,  256, 0, stream>>>(Wout, wout_bf,  1048576 / 4);
  zero_f32<<<32, 256, 0, stream>>>(ksum, 8192);

  // GEMM1 (256^2 read-ahead pipeline): x @ Wqkv^T -> q + kT/vT + ksum
  gemm256<0><<<dim3(128, 12, 1), 512, 0, stream>>>(
      x_bf, wqkv_bf, qbuf, 32768, 3072, 1024, 1024, 1024, 1024,
      0, 0, 0, nullptr, nullptr, kT, vT, ksum);

  // z = 1/(q·ksum + eps)
  z_kernel<<<8192, 256, 0, stream>>>(qbuf, ksum, z);

  // GEMM2 (batched 8): kv[d][e] = kT_b @ vT_b^T  (K=4096)
  gemm_abT<1><<<dim3(8, 8, 8), 256, 0, stream>>>(
      kT, vT, kv, 1024, 1024, 4096, 4096, 4096, 1024,
      4194304, 4194304, 1048576, nullptr, nullptr, nullptr, nullptr, nullptr);

  // GEMM2b (batched 8): kvwT[f][d] = Wout @ kv_b^T  (K=1024)
  gemm_abT<1><<<dim3(8, 8, 8), 256, 0, stream>>>(
      wout_bf, kv, kvwT, 1024, 1024, 1024, 1024, 1024, 1024,
      0, 1048576, 1048576, nullptr, nullptr, nullptr, nullptr, nullptr);

  // GEMM3 (256^2 read-ahead pipeline, batched 8): out = z[n]*(q@kvwT^T)+b_out
  gemm256<2><<<dim3(16, 4, 8), 512, 0, stream>>>(
      qbuf, kvwT, d_out, 4096, 1024, 1024, 1024, 1024, 1024,
      4194304, 1048576, 4194304, z, bout, nullptr, nullptr, nullptr);
}

// Round 5
// 697.419 us; speedup vs baseline: 1.0983x; 1.0983x over previous
//
#include <hip/hip_runtime.h>

// LinearAttention on MI355X (gfx950), bf16 MFMA pipeline.
// R6: revert gemm256 to the R1 schedule (verified 246 µs GEMM1; R5's main-loop
// vmcnt(0) drain violated T4 and regressed). NEW: GEMM2 (kT@vT^T, K=4096) moves
// from the 128^2 drain-per-K-step kernel to split-K=2 gemm256 (MODE 3, f32
// partials into dead x_bf, 256 blocks = 1/CU one round) + reduce_kv kernel.
// XCD swizzle gets a small-grid guard (formula invalid for gridDim.x<8).

#define EPS 1e-6f

using u16 = unsigned short;
typedef __attribute__((ext_vector_type(4))) float f32x4;
typedef __attribute__((ext_vector_type(8))) __bf16 bf16x8;

__device__ __forceinline__ u16 f2b(float f) {
  unsigned u = __builtin_bit_cast(unsigned, f);
  u += 0x7FFFu + ((u >> 16) & 1u);     // RNE
  return (u16)(u >> 16);
}
__device__ __forceinline__ float b2f(u16 h) {
  return __builtin_bit_cast(float, (unsigned)h << 16);
}

typedef const __attribute__((address_space(1))) void* gas1_t;
typedef __attribute__((address_space(3))) void* las3_t;

__device__ __forceinline__ void load16_to_lds(const void* g, void* l) {
  __builtin_amdgcn_global_load_lds((gas1_t)g, (las3_t)l, 16, 0, 0);
}

#define BARRIER() do { asm volatile("" ::: "memory"); __builtin_amdgcn_s_barrier(); asm volatile("" ::: "memory"); } while (0)
#define WAITL0()  asm volatile("s_waitcnt lgkmcnt(0)" ::: "memory")
#define WAITV(n)  asm volatile("s_waitcnt vmcnt(" #n ")" ::: "memory")
#define MFMA16(a, b, c) __builtin_amdgcn_mfma_f32_16x16x32_bf16((a), (b), (c), 0, 0, 0)

// Stage one 128x64 half-tile: LDS dest linear (global_load_lds requirement),
// global source column pre-swizzled with the involution chunk ^= (row&7) so the
// swizzled ds_read side reads the right bytes (rule: both-sides-or-neither).
__device__ __forceinline__ void stage_half(const u16* g, int ld, u16* l,
                                           int r0, int csw, int woff) {
  load16_to_lds(g + (long long)r0 * ld + csw, l + woff);
  load16_to_lds(g + (long long)(r0 + 64) * ld + csw, l + 4096 + woff);
}

// ---------------------------------------------------------------------------
// 256x256-tile, BK=64, 8 waves (2M x 4N), double-buffered 128 KiB LDS,
// 4 phases per K-tile, counted vmcnt(6) (3 half-tiles always in flight).
// R1-verified schedule. C = A * B^T.  A: [M][K] bf16, B: [N][K] bf16.
// MODE 0: GEMM1 fused epilogue (q n-major relu+eps / kT,vT transposed / ksum).
// MODE 1: bf16 out.  MODE 2: f32 out, v*z[row] + bias[col].
// MODE 3: split-K partial, f32 plain out; bz decodes {batch=bz&7, kh=bz>>3},
//         A/B offset by kh*2048 columns (K passed = 2048, lda/ldb = 4096).
// Requires M%256==0, N%256==0, K%64==0; XCD swizzle only when gridDim.x>=8
// (and then (gridDim.x*gridDim.y)%8==0).
// ---------------------------------------------------------------------------
template<int MODE>
__global__ __launch_bounds__(512, 2) void gemm256(
    const u16* __restrict__ A, const u16* __restrict__ B, void* __restrict__ Cv,
    int M, int N, int K, int lda, int ldb, int ldc,
    long long sA, long long sB, long long sC,
    const float* __restrict__ zvec, const float* __restrict__ bias,
    u16* __restrict__ kT, u16* __restrict__ vT, float* __restrict__ ksum)
{
  __shared__ __align__(16) u16 shA[32768];   // [2 buf][2 half][128 r][8 chunks*8]
  __shared__ __align__(16) u16 shB[32768];

  const int tid  = threadIdx.x;
  const int lane = tid & 63, wave = tid >> 6;
  const int wr = wave >> 2, wc = wave & 3;           // 2M x 4N wave grid
  const int quad = lane >> 4, lc = lane & 15;

  // XCD-aware swizzle (bijective when grid multiple of 8); identity for small grids
  const int TN = gridDim.y;
  const int lin = blockIdx.x + gridDim.x * blockIdx.y;
  int bm, bn;
  if (gridDim.x >= 8) {
    const int xcd = lin & 7, g = lin >> 3;
    bm = (g / TN) * 8 + xcd;
    bn = g % TN;
  } else {
    bm = blockIdx.x;
    bn = blockIdx.y;
  }
  const int bz = blockIdx.z;
  const u16* Ab;
  const u16* Bb;
  if (MODE == 3) {
    const int bb = bz & 7, kh = bz >> 3;
    Ab = A + (long long)bb * sA + kh * 2048;
    Bb = B + (long long)bb * sB + kh * 2048;
  } else {
    Ab = A + (long long)bz * sA;
    Bb = B + (long long)bz * sB;
  }

  // staging addressing: thread covers chunks {tid, 512+tid} of each half-tile
  const int r0   = tid >> 3;                                   // rows 0..63 (+64)
  const int csw  = (((tid & 7) ^ ((tid >> 3) & 7)) << 3);      // inverse-swz col
  const int woff = wave * 512;                                 // wave-uniform LDS off

  // fragment read addressing (swizzled chunk index, constant per lane)
  const int ch0 = ((quad ^ (lane & 7)) << 3);                  // ksub 0
  const int ch1 = (((4 + quad) ^ (lane & 7)) << 3);            // ksub 1
  const int aRow = wr * 128 + lc;
  const int bRow = wc * 64 + lc;

  const int NT = K >> 6;

  f32x4 acc[8][4];
  #pragma unroll
  for (int i = 0; i < 8; ++i)
    #pragma unroll
    for (int j = 0; j < 4; ++j) acc[i][j] = f32x4{0.f, 0.f, 0.f, 0.f};

  auto stA = [&](int h, int t) {
    stage_half(Ab + ((long long)bm * 256 + h * 128) * lda + t * 64, lda,
               shA + (t & 1) * 16384 + h * 8192, r0, csw, woff);
  };
  auto stB = [&](int h, int t) {
    stage_half(Bb + ((long long)bn * 256 + h * 128) * ldb + t * 64, ldb,
               shB + (t & 1) * 16384 + h * 8192, r0, csw, woff);
  };

  // prologue: tile0 fully + tile1 {A0,A1,B0}; keep tile1's 3 halves in flight
  stA(0, 0); stA(1, 0); stB(0, 0); stB(1, 0);
  if (NT > 1) { stA(0, 1); stA(1, 1); stB(0, 1); WAITV(6); }
  else        { WAITV(0); }
  BARRIER();

  for (int t = 0; t < NT; ++t) {
    const u16* aB = shA + (t & 1) * 16384;
    const u16* bB = shB + (t & 1) * 16384;
    bf16x8 aF[4][2], b01[2][2], b23[2][2];

    // ---- phase 1: read A[i0-3]+B[j0-1]; stage B1(t+1) [other buf]; mfma (0,0)
    #pragma unroll
    for (int i = 0; i < 4; ++i) {
      aF[i][0] = *(const bf16x8*)&aB[(aRow + i * 16) * 64 + ch0];
      aF[i][1] = *(const bf16x8*)&aB[(aRow + i * 16) * 64 + ch1];
    }
    #pragma unroll
    for (int j = 0; j < 2; ++j) {
      b01[j][0] = *(const bf16x8*)&bB[(bRow + j * 16) * 64 + ch0];
      b01[j][1] = *(const bf16x8*)&bB[(bRow + j * 16) * 64 + ch1];
    }
    if (t + 1 < NT) stB(1, t + 1);
    BARRIER(); WAITL0();
    __builtin_amdgcn_s_setprio(1);
    #pragma unroll
    for (int i = 0; i < 4; ++i)
      #pragma unroll
      for (int j = 0; j < 2; ++j) {
        acc[i][j] = MFMA16(aF[i][0], b01[j][0], acc[i][j]);
        acc[i][j] = MFMA16(aF[i][1], b01[j][1], acc[i][j]);
      }
    __builtin_amdgcn_s_setprio(0);
    BARRIER();

    // ---- phase 2: read B[j2-3]; mfma (0,1)
    #pragma unroll
    for (int j = 0; j < 2; ++j) {
      b23[j][0] = *(const bf16x8*)&bB[(bRow + (2 + j) * 16) * 64 + ch0];
      b23[j][1] = *(const bf16x8*)&bB[(bRow + (2 + j) * 16) * 64 + ch1];
    }
    BARRIER(); WAITL0();
    __builtin_amdgcn_s_setprio(1);
    #pragma unroll
    for (int i = 0; i < 4; ++i)
      #pragma unroll
      for (int j = 0; j < 2; ++j) {
        acc[i][2 + j] = MFMA16(aF[i][0], b23[j][0], acc[i][2 + j]);
        acc[i][2 + j] = MFMA16(aF[i][1], b23[j][1], acc[i][2 + j]);
      }
    __builtin_amdgcn_s_setprio(0);
    BARRIER();

    // ---- phase 3: read A[i4-7]; B region of this buf dead -> stage B0(t+2); mfma (1,0)
    #pragma unroll
    for (int i = 0; i < 4; ++i) {
      aF[i][0] = *(const bf16x8*)&aB[(aRow + (4 + i) * 16) * 64 + ch0];
      aF[i][1] = *(const bf16x8*)&aB[(aRow + (4 + i) * 16) * 64 + ch1];
    }
    if (t + 2 < NT) stB(0, t + 2);
    BARRIER(); WAITL0();
    __builtin_amdgcn_s_setprio(1);
    #pragma unroll
    for (int i = 0; i < 4; ++i)
      #pragma unroll
      for (int j = 0; j < 2; ++j) {
        acc[4 + i][j] = MFMA16(aF[i][0], b01[j][0], acc[4 + i][j]);
        acc[4 + i][j] = MFMA16(aF[i][1], b01[j][1], acc[4 + i][j]);
      }
    __builtin_amdgcn_s_setprio(0);
    BARRIER();

    // ---- phase 4: A region of this buf dead -> stage A0,A1(t+2); mfma (1,1);
    //      counted boundary wait: newest 6 loads (t+2's 3 halves) stay in flight
    if (t + 2 < NT) { stA(0, t + 2); stA(1, t + 2); }
    BARRIER(); WAITL0();
    __builtin_amdgcn_s_setprio(1);
    #pragma unroll
    for (int i = 0; i < 4; ++i)
      #pragma unroll
      for (int j = 0; j < 2; ++j) {
        acc[4 + i][2 + j] = MFMA16(aF[i][0], b23[j][0], acc[4 + i][2 + j]);
        acc[4 + i][2 + j] = MFMA16(aF[i][1], b23[j][1], acc[4 + i][2 + j]);
      }
    __builtin_amdgcn_s_setprio(0);
    if (t + 2 < NT) { WAITV(6); } else { WAITV(0); }
    BARRIER();
  }

  // ---- epilogue.  C/D layout (m89): col = lane&15, row = (lane>>4)*4 + reg
  const long long rowb = (long long)bm * 256 + wr * 128 + quad * 4;
  const int colb = bn * 256 + wc * 64 + lc;

  if (MODE == 0) {
    const int region = colb >> 10;           // 0:q 1:k 2:v (tile stays in-region)
    if (region == 0) {
      u16* q = (u16*)Cv;
      #pragma unroll
      for (int i = 0; i < 8; ++i)
        #pragma unroll
        for (int j = 0; j < 4; ++j) {
          const int col = colb + j * 16;
          #pragma unroll
          for (int r = 0; r < 4; ++r) {
            const long long row = rowb + i * 16 + r;
            q[row * ldc + col] = f2b(fmaxf(acc[i][j][r], 0.f) + EPS);
          }
        }
    } else {
      const bool isk = (region == 1);
      const int b = (int)(rowb >> 12);       // batch (256-row tile within batch)
      u16* dst = (isk ? kT : vT) + (long long)b * 1024 * 4096;
      const int nloc = (int)(rowb & 4095);
      #pragma unroll
      for (int j = 0; j < 4; ++j) {
        const int d = colb + j * 16 - region * 1024;
        float s = 0.f;
        #pragma unroll
        for (int i = 0; i < 8; ++i) {
          ushort4 pk;
          #pragma unroll
          for (int r = 0; r < 4; ++r) {
            float v = acc[i][j][r];
            if (isk) { v = fmaxf(v, 0.f) + EPS; s += v; }
            (&pk.x)[r] = f2b(v);
          }
          *(ushort4*)(dst + (long long)d * 4096 + nloc + i * 16) = pk;
        }
        if (isk) {
          s += __shfl_xor(s, 16);            // reduce 4 quads -> 128 n-rows/wave
          s += __shfl_xor(s, 32);
          if (quad == 0) atomicAdd(&ksum[b * 1024 + d], s);
        }
      }
    }
  } else if (MODE == 2) {
    float* out = (float*)Cv + (long long)bz * sC;
    #pragma unroll
    for (int i = 0; i < 8; ++i)
      #pragma unroll
      for (int j = 0; j < 4; ++j) {
        const int col = colb + j * 16;
        const float bj = bias[col];
        #pragma unroll
        for (int r = 0; r < 4; ++r) {
          const long long row = rowb + i * 16 + r;
          out[row * ldc + col] = acc[i][j][r] * zvec[(long long)bz * M + row] + bj;
        }
      }
  } else if (MODE == 3) {
    float* out = (float*)Cv + (long long)bz * sC;
    #pragma unroll
    for (int i = 0; i < 8; ++i)
      #pragma unroll
      for (int j = 0; j < 4; ++j) {
        const int col = colb + j * 16;
        #pragma unroll
        for (int r = 0; r < 4; ++r) {
          const long long row = rowb + i * 16 + r;
          out[row * ldc + col] = acc[i][j][r];
        }
      }
  } else {
    u16* out = (u16*)Cv + (long long)bz * sC;
    #pragma unroll
    for (int i = 0; i < 8; ++i)
      #pragma unroll
      for (int j = 0; j < 4; ++j) {
        const int col = colb + j * 16;
        #pragma unroll
        for (int r = 0; r < 4; ++r) {
          const long long row = rowb + i * 16 + r;
          out[row * ldc + col] = f2b(acc[i][j][r]);
        }
      }
  }
}

// ---------------------------------------------------------------------------
// 128^2-tile kernel (m97 structure) — kept for GEMM2b (small, K=1024).
// C = A * B^T.  MODE 1: bf16 out, plain.
// ---------------------------------------------------------------------------
template<int MODE>
__global__ __launch_bounds__(256) void gemm_abT(
    const u16* __restrict__ A, const u16* __restrict__ B, void* __restrict__ Cv,
    int M, int N, int K, int lda, int ldb, int ldc,
    long long sA, long long sB, long long sC,
    const float* __restrict__ zvec, const float* __restrict__ bias,
    u16* __restrict__ kT, u16* __restrict__ vT, float* __restrict__ ksum)
{
  __shared__ u16 lA[128 * 32];
  __shared__ u16 lB[128 * 32];
  const int tid  = threadIdx.x;
  const int wave = tid >> 6, lane = tid & 63;
  const int TN = gridDim.y;
  const int lin = blockIdx.x + gridDim.x * blockIdx.y;
  const int xcd = lin & 7, g = lin >> 3;
  const int bm = (g / TN) * 8 + xcd;
  const int bn = g % TN;
  const int bz = blockIdx.z;
  const u16* Ab = A + (long long)bz * sA;
  const u16* Bb = B + (long long)bz * sB;

  const int c0 = wave * 64 + lane;
  const int c1 = 256 + c0;
  const u16* gA0 = Ab + (long long)(bm * 128 + (c0 >> 2)) * lda + (c0 & 3) * 8;
  const u16* gA1 = Ab + (long long)(bm * 128 + (c1 >> 2)) * lda + (c1 & 3) * 8;
  const u16* gB0 = Bb + (long long)(bn * 128 + (c0 >> 2)) * ldb + (c0 & 3) * 8;
  const u16* gB1 = Bb + (long long)(bn * 128 + (c1 >> 2)) * ldb + (c1 & 3) * 8;
  u16* lA0 = &lA[(wave * 64) * 8];
  u16* lA1 = &lA[(256 + wave * 64) * 8];
  u16* lB0 = &lB[(wave * 64) * 8];
  u16* lB1 = &lB[(256 + wave * 64) * 8];

  const int wm = (wave & 1) * 64, wn = (wave >> 1) * 64;
  const int aoff = (wm + (lane & 15)) * 32 + (lane >> 4) * 8;
  const int boff = (wn + (lane & 15)) * 32 + (lane >> 4) * 8;

  f32x4 acc[4][4];
  #pragma unroll
  for (int i = 0; i < 4; i++)
    #pragma unroll
    for (int j = 0; j < 4; j++) acc[i][j] = f32x4{0.f, 0.f, 0.f, 0.f};

  for (int k0 = 0; k0 < K; k0 += 32) {
    load16_to_lds(gA0 + k0, lA0);
    load16_to_lds(gA1 + k0, lA1);
    load16_to_lds(gB0 + k0, lB0);
    load16_to_lds(gB1 + k0, lB1);
    __syncthreads();
    bf16x8 af[4], bfv[4];
    #pragma unroll
    for (int i = 0; i < 4; i++) af[i]  = *(const bf16x8*)&lA[aoff + i * 16 * 32];
    #pragma unroll
    for (int j = 0; j < 4; j++) bfv[j] = *(const bf16x8*)&lB[boff + j * 16 * 32];
    #pragma unroll
    for (int i = 0; i < 4; i++)
      #pragma unroll
      for (int j = 0; j < 4; j++)
        acc[i][j] = MFMA16(af[i], bfv[j], acc[i][j]);
    __syncthreads();
  }

  const int quad = lane >> 4, lc = lane & 15;
  const int rowb = bm * 128 + wm + quad * 4;
  const int colb = bn * 128 + wn + lc;

  #pragma unroll
  for (int i = 0; i < 4; i++) {
    #pragma unroll
    for (int j = 0; j < 4; j++) {
      const int col = colb + j * 16;
      float bj = 0.f;
      if (MODE == 2) bj = bias[col];
      #pragma unroll
      for (int r = 0; r < 4; r++) {
        const int row = rowb + i * 16 + r;
        float v = acc[i][j][r];
        if (MODE == 1) {
          ((u16*)Cv + (long long)bz * sC)[(long long)row * ldc + col] = f2b(v);
        } else if (MODE == 2) {
          float zz = zvec[(long long)bz * M + row];
          ((float*)Cv + (long long)bz * sC)[(long long)row * ldc + col] = v * zz + bj;
        }
      }
    }
  }
  (void)kT; (void)vT; (void)ksum;
}

// fp32 -> bf16 bulk convert (vectorized, grid-stride)
__global__ void cvt_f32_bf16(const float* __restrict__ s, u16* __restrict__ d, int n4) {
  int i = blockIdx.x * blockDim.x + threadIdx.x;
  int st = gridDim.x * blockDim.x;
  for (; i < n4; i += st) {
    float4 f = ((const float4*)s)[i];
    uint2 o;
    o.x = (unsigned)f2b(f.x) | ((unsigned)f2b(f.y) << 16);
    o.y = (unsigned)f2b(f.z) | ((unsigned)f2b(f.w) << 16);
    ((uint2*)d)[i] = o;
  }
}

__global__ void zero_f32(float* __restrict__ p, int n) {
  int i = blockIdx.x * blockDim.x + threadIdx.x;
  if (i < n) p[i] = 0.f;
}

// kv[b][i] = bf16(p[b][i] + p[8+b][i]); p = [16][1M] f32 partials, kv bf16 8M.
__global__ void reduce_kv(const float* __restrict__ p, u16* __restrict__ kv) {
  long long idx = blockIdx.x * blockDim.x + threadIdx.x;   // float4 units
  const long long st = (long long)gridDim.x * blockDim.x;
  for (; idx < 2097152; idx += st) {                        // 8M f32 / 4
    const long long b = idx >> 18;                          // 256K float4/batch
    const long long i = idx & 262143;
    float4 x = ((const float4*)p)[b * 262144 + i];
    float4 y = ((const float4*)p)[(8 + b) * 262144 + i];
    float4 s;
    s.x = x.x + y.x; s.y = x.y + y.y; s.z = x.z + y.z; s.w = x.w + y.w;
    uint2 o;
    o.x = (unsigned)f2b(s.x) | ((unsigned)f2b(s.y) << 16);
    o.y = (unsigned)f2b(s.z) | ((unsigned)f2b(s.w) << 16);
    ((uint2*)kv)[b * 262144 + i] = o;
  }
}

// z[row] = 1/(q[row,:]·ksum[b,:] + eps); one wave per row; q is [32768][1024]
__global__ void z_kernel(const u16* __restrict__ qbuf, const float* __restrict__ ksum,
                         float* __restrict__ z) {
  const int row  = blockIdx.x * 4 + (threadIdx.x >> 6);
  const int lane = threadIdx.x & 63;
  const int b = row >> 12;
  const uint4* q = (const uint4*)(qbuf + (long long)row * 1024);
  const float* ks = ksum + b * 1024;
  float s = 0.f;
  #pragma unroll
  for (int c = 0; c < 2; c++) {
    int idx = lane + c * 64;
    uint4 d = q[idx];
    unsigned w[4] = {d.x, d.y, d.z, d.w};
    const float* kk = ks + idx * 8;
    #pragma unroll
    for (int qq = 0; qq < 4; qq++)
      s += b2f((u16)(w[qq] & 0xFFFF)) * kk[qq * 2]
         + b2f((u16)(w[qq] >> 16))    * kk[qq * 2 + 1];
  }
  #pragma unroll
  for (int o = 32; o > 0; o >>= 1) s += __shfl_down(s, o);
  if (lane == 0) z[row] = 1.0f / (s + EPS);
}

extern "C" void kernel_launch(void* const* d_in, const int* in_sizes, int n_in,
                              void* d_out, int out_size, void* d_ws, size_t ws_size,
                              hipStream_t stream) {
  const float* x    = (const float*)d_in[0];   // [8,4096,1024]
  const float* Wqkv = (const float*)d_in[1];   // [3072,1024]
  const float* Wout = (const float*)d_in[2];   // [1024,1024]
  const float* bout = (const float*)d_in[3];   // [1024]

  char* ws = (char*)d_ws;                      // ~310.6 MiB
  u16* x_bf    = (u16*)(ws + 0);               // 64 MiB (dead after GEMM1 -> f32 partials)
  u16* qbuf    = (u16*)(ws + 67108864);        // 64 MiB [32768][1024]
  u16* kT      = (u16*)(ws + 134217728);       // 64 MiB [8][1024][4096]
  u16* vT      = (u16*)(ws + 201326592);       // 64 MiB [8][1024][4096]
  u16* wqkv_bf = (u16*)(ws + 268435456);       // 6 MiB
  u16* wout_bf = (u16*)(ws + 274726912);       // 2 MiB
  u16* kv      = (u16*)(ws + 276824064);       // 16 MiB [8][1024][1024]
  u16* kvwT    = (u16*)(ws + 293601280);       // 16 MiB [8][1024][1024]
  float* ksum  = (float*)(ws + 310378496);     // 32 KiB [8][1024]
  float* z     = (float*)(ws + 310411264);     // 128 KiB [32768]

  cvt_f32_bf16<<<4096, 256, 0, stream>>>(x,    x_bf,    33554432 / 4);
  cvt_f32_bf16<<<1024, 256, 0, stream>>>(Wqkv, wqkv_bf,  3145728 / 4);
  cvt_f32_bf16<<<512,  256, 0, stream>>>(Wout, wout_bf,  1048576 / 4);
  zero_f32<<<32, 256, 0, stream>>>(ksum, 8192);

  // GEMM1 (256^2, R1 schedule): x @ Wqkv^T -> q (n-major) + kT/vT + ksum
  gemm256<0><<<dim3(128, 12, 1), 512, 0, stream>>>(
      x_bf, wqkv_bf, qbuf, 32768, 3072, 1024, 1024, 1024, 1024,
      0, 0, 0, nullptr, nullptr, kT, vT, ksum);

  // z = 1/(q·ksum + eps)
  z_kernel<<<8192, 256, 0, stream>>>(qbuf, ksum, z);

  // GEMM2 (split-K=2 on gemm256): partial[kh*8+b] = kT_b[:,kh] @ vT_b[:,kh]^T
  // 256 blocks = 1/CU, one round; f32 partials in dead x_bf (64 MiB).
  gemm256<3><<<dim3(4, 4, 16), 512, 0, stream>>>(
      kT, vT, (float*)x_bf, 1024, 1024, 2048, 4096, 4096, 1024,
      4194304, 4194304, 1048576, nullptr, nullptr, nullptr, nullptr, nullptr);

  // kv = bf16(partial[b] + partial[8+b])
  reduce_kv<<<2048, 256, 0, stream>>>((const float*)x_bf, kv);

  // GEMM2b (batched 8): kvwT[f][d] = Wout @ kv_b^T  (K=1024)
  gemm_abT<1><<<dim3(8, 8, 8), 256, 0, stream>>>(
      wout_bf, kv, kvwT, 1024, 1024, 1024, 1024, 1024, 1024,
      0, 1048576, 1048576, nullptr, nullptr, nullptr, nullptr, nullptr);

  // GEMM3 (256^2, batched 8): out = z[n]*(q_b @ kvwT_b^T) + b_out, fp32
  gemm256<2><<<dim3(16, 4, 8), 512, 0, stream>>>(
      qbuf, kvwT, d_out, 4096, 1024, 1024, 1024, 1024, 1024,
      4194304, 1048576, 4194304, z, bout, nullptr, nullptr, nullptr);
}

// Round 7
// 682.347 us; speedup vs baseline: 1.1226x; 1.0221x over previous
//
#include <hip/hip_runtime.h>

// LinearAttention on MI355X (gfx950), bf16 MFMA pipeline.
// R8: de-over-synchronization, race-free form. 3 barriers/K-tile (was 8), no
// forced lgkm drains (compiler emits counted lgkm before each MFMA). Each LDS
// staging overwrite is issued AFTER the barrier that follows its region's last
// consuming MFMA (counted-lgkm proves reads retired; barrier publishes it):
//   C1: rd aF,b01; stB1(t+1)[other buf]; mfma00
//   C2: rd b23; mfma01
//   C3: BAR; stB0(t+2); rd aG; mfma10
//   C4: BAR; stA(t+2); mfma11; vmcnt(6); BAR
// (R7 issued stagings BEFORE the handoff barrier with un-drained reads — a
// DMA-vs-ds_read race; fixed here.) T4 counted vmcnt(6) intact.
// GEMM2 stays split-K=2 on gemm256; GEMM2b on the 128^2 kernel.

#define EPS 1e-6f

using u16 = unsigned short;
typedef __attribute__((ext_vector_type(4))) float f32x4;
typedef __attribute__((ext_vector_type(8))) __bf16 bf16x8;

__device__ __forceinline__ u16 f2b(float f) {
  unsigned u = __builtin_bit_cast(unsigned, f);
  u += 0x7FFFu + ((u >> 16) & 1u);     // RNE
  return (u16)(u >> 16);
}
__device__ __forceinline__ float b2f(u16 h) {
  return __builtin_bit_cast(float, (unsigned)h << 16);
}

typedef const __attribute__((address_space(1))) void* gas1_t;
typedef __attribute__((address_space(3))) void* las3_t;

__device__ __forceinline__ void load16_to_lds(const void* g, void* l) {
  __builtin_amdgcn_global_load_lds((gas1_t)g, (las3_t)l, 16, 0, 0);
}

#define BARRIER() do { asm volatile("" ::: "memory"); __builtin_amdgcn_s_barrier(); asm volatile("" ::: "memory"); } while (0)
#define WAITV(n)  asm volatile("s_waitcnt vmcnt(" #n ")" ::: "memory")
#define MFMA16(a, b, c) __builtin_amdgcn_mfma_f32_16x16x32_bf16((a), (b), (c), 0, 0, 0)

// Stage one 128x64 half-tile: LDS dest linear (global_load_lds requirement),
// global source column pre-swizzled with the involution chunk ^= (row&7) so the
// swizzled ds_read side reads the right bytes (rule: both-sides-or-neither).
__device__ __forceinline__ void stage_half(const u16* g, int ld, u16* l,
                                           int r0, int csw, int woff) {
  load16_to_lds(g + (long long)r0 * ld + csw, l + woff);
  load16_to_lds(g + (long long)(r0 + 64) * ld + csw, l + 4096 + woff);
}

// ---------------------------------------------------------------------------
// 256x256-tile, BK=64, 8 waves (2M x 4N), double-buffered 128 KiB LDS.
// MODE 0: GEMM1 fused epilogue (q n-major relu+eps / kT,vT transposed / ksum).
// MODE 1: bf16 out.  MODE 2: f32 out, v*z[row] + bias[col].
// MODE 3: split-K partial, f32 plain out; bz = {batch=bz&7, kh=bz>>3}.
// Requires M%256==0, N%256==0, K%64==0; XCD swizzle only when gridDim.x>=8.
// ---------------------------------------------------------------------------
template<int MODE>
__global__ __launch_bounds__(512, 2) void gemm256(
    const u16* __restrict__ A, const u16* __restrict__ B, void* __restrict__ Cv,
    int M, int N, int K, int lda, int ldb, int ldc,
    long long sA, long long sB, long long sC,
    const float* __restrict__ zvec, const float* __restrict__ bias,
    u16* __restrict__ kT, u16* __restrict__ vT, float* __restrict__ ksum)
{
  __shared__ __align__(16) u16 shA[32768];   // [2 buf][2 half][128 r][8 chunks*8]
  __shared__ __align__(16) u16 shB[32768];

  const int tid  = threadIdx.x;
  const int lane = tid & 63, wave = tid >> 6;
  const int wr = wave >> 2, wc = wave & 3;           // 2M x 4N wave grid
  const int quad = lane >> 4, lc = lane & 15;

  // XCD-aware swizzle (bijective when grid multiple of 8); identity for small grids
  const int TN = gridDim.y;
  const int lin = blockIdx.x + gridDim.x * blockIdx.y;
  int bm, bn;
  if (gridDim.x >= 8) {
    const int xcd = lin & 7, g = lin >> 3;
    bm = (g / TN) * 8 + xcd;
    bn = g % TN;
  } else {
    bm = blockIdx.x;
    bn = blockIdx.y;
  }
  const int bz = blockIdx.z;
  const u16* Ab;
  const u16* Bb;
  if (MODE == 3) {
    const int bb = bz & 7, kh = bz >> 3;
    Ab = A + (long long)bb * sA + kh * 2048;
    Bb = B + (long long)bb * sB + kh * 2048;
  } else {
    Ab = A + (long long)bz * sA;
    Bb = B + (long long)bz * sB;
  }

  // staging addressing: thread covers chunks {tid, 512+tid} of each half-tile
  const int r0   = tid >> 3;                                   // rows 0..63 (+64)
  const int csw  = (((tid & 7) ^ ((tid >> 3) & 7)) << 3);      // inverse-swz col
  const int woff = wave * 512;                                 // wave-uniform LDS off

  // fragment read addressing (swizzled chunk index, constant per lane)
  const int ch0 = ((quad ^ (lane & 7)) << 3);                  // ksub 0
  const int ch1 = (((4 + quad) ^ (lane & 7)) << 3);            // ksub 1
  const int aRow = wr * 128 + lc;
  const int bRow = wc * 64 + lc;

  const int NT = K >> 6;

  f32x4 acc[8][4];
  #pragma unroll
  for (int i = 0; i < 8; ++i)
    #pragma unroll
    for (int j = 0; j < 4; ++j) acc[i][j] = f32x4{0.f, 0.f, 0.f, 0.f};

  auto stA = [&](int h, int t) {
    stage_half(Ab + ((long long)bm * 256 + h * 128) * lda + t * 64, lda,
               shA + (t & 1) * 16384 + h * 8192, r0, csw, woff);
  };
  auto stB = [&](int h, int t) {
    stage_half(Bb + ((long long)bn * 256 + h * 128) * ldb + t * 64, ldb,
               shB + (t & 1) * 16384 + h * 8192, r0, csw, woff);
  };

  // prologue: tile0 fully + tile1 {A0,A1,B0}; keep tile1's 3 halves in flight
  stA(0, 0); stA(1, 0); stB(0, 0); stB(1, 0);
  if (NT > 1) { stA(0, 1); stA(1, 1); stB(0, 1); WAITV(6); }
  else        { WAITV(0); }
  BARRIER();

  for (int t = 0; t < NT; ++t) {
    const u16* aB = shA + (t & 1) * 16384;
    const u16* bB = shB + (t & 1) * 16384;
    bf16x8 aF[4][2], b01[2][2], b23[2][2];

    // ---- C1: read aF + b01; stage B1(t+1) into OTHER buf (region dead since
    //      the end-of-tile barrier of t-1); mfma (0,0)
    #pragma unroll
    for (int i = 0; i < 4; ++i) {
      aF[i][0] = *(const bf16x8*)&aB[(aRow + i * 16) * 64 + ch0];
      aF[i][1] = *(const bf16x8*)&aB[(aRow + i * 16) * 64 + ch1];
    }
    #pragma unroll
    for (int j = 0; j < 2; ++j) {
      b01[j][0] = *(const bf16x8*)&bB[(bRow + j * 16) * 64 + ch0];
      b01[j][1] = *(const bf16x8*)&bB[(bRow + j * 16) * 64 + ch1];
    }
    if (t + 1 < NT) stB(1, t + 1);
    __builtin_amdgcn_s_setprio(1);
    #pragma unroll
    for (int i = 0; i < 4; ++i)
      #pragma unroll
      for (int j = 0; j < 2; ++j) {
        acc[i][j] = MFMA16(aF[i][0], b01[j][0], acc[i][j]);
        acc[i][j] = MFMA16(aF[i][1], b01[j][1], acc[i][j]);
      }
    __builtin_amdgcn_s_setprio(0);

    // ---- C2: read b23; mfma (0,1)   (no barrier)
    #pragma unroll
    for (int j = 0; j < 2; ++j) {
      b23[j][0] = *(const bf16x8*)&bB[(bRow + (2 + j) * 16) * 64 + ch0];
      b23[j][1] = *(const bf16x8*)&bB[(bRow + (2 + j) * 16) * 64 + ch1];
    }
    __builtin_amdgcn_s_setprio(1);
    #pragma unroll
    for (int i = 0; i < 4; ++i)
      #pragma unroll
      for (int j = 0; j < 2; ++j) {
        acc[i][2 + j] = MFMA16(aF[i][0], b23[j][0], acc[i][2 + j]);
        acc[i][2 + j] = MFMA16(aF[i][1], b23[j][1], acc[i][2 + j]);
      }
    __builtin_amdgcn_s_setprio(0);

    // ---- C3: BAR (mfma01 above drained every wave's B-reads of this buf) ->
    //      stage B0(t+2) into current buf is safe; read aG; mfma (1,0)
    BARRIER();
    if (t + 2 < NT) stB(0, t + 2);
    #pragma unroll
    for (int i = 0; i < 4; ++i) {
      aF[i][0] = *(const bf16x8*)&aB[(aRow + (4 + i) * 16) * 64 + ch0];
      aF[i][1] = *(const bf16x8*)&aB[(aRow + (4 + i) * 16) * 64 + ch1];
    }
    __builtin_amdgcn_s_setprio(1);
    #pragma unroll
    for (int i = 0; i < 4; ++i)
      #pragma unroll
      for (int j = 0; j < 2; ++j) {
        acc[4 + i][j] = MFMA16(aF[i][0], b01[j][0], acc[4 + i][j]);
        acc[4 + i][j] = MFMA16(aF[i][1], b01[j][1], acc[4 + i][j]);
      }
    __builtin_amdgcn_s_setprio(0);

    // ---- C4: BAR (mfma10 drained every wave's A-reads) -> stage A(t+2) into
    //      current buf is safe; mfma (1,1); counted vmcnt(6): the 6 newest
    //      outstanding loads are exactly t+2's -> tile t+1 fully landed; BAR
    BARRIER();
    if (t + 2 < NT) { stA(0, t + 2); stA(1, t + 2); }
    __builtin_amdgcn_s_setprio(1);
    #pragma unroll
    for (int i = 0; i < 4; ++i)
      #pragma unroll
      for (int j = 0; j < 2; ++j) {
        acc[4 + i][2 + j] = MFMA16(aF[i][0], b23[j][0], acc[4 + i][2 + j]);
        acc[4 + i][2 + j] = MFMA16(aF[i][1], b23[j][1], acc[4 + i][2 + j]);
      }
    __builtin_amdgcn_s_setprio(0);
    if (t + 2 < NT) { WAITV(6); } else { WAITV(0); }
    BARRIER();
  }

  // ---- epilogue.  C/D layout (m89): col = lane&15, row = (lane>>4)*4 + reg
  const long long rowb = (long long)bm * 256 + wr * 128 + quad * 4;
  const int colb = bn * 256 + wc * 64 + lc;

  if (MODE == 0) {
    const int region = colb >> 10;           // 0:q 1:k 2:v (tile stays in-region)
    if (region == 0) {
      u16* q = (u16*)Cv;
      #pragma unroll
      for (int i = 0; i < 8; ++i)
        #pragma unroll
        for (int j = 0; j < 4; ++j) {
          const int col = colb + j * 16;
          #pragma unroll
          for (int r = 0; r < 4; ++r) {
            const long long row = rowb + i * 16 + r;
            q[row * ldc + col] = f2b(fmaxf(acc[i][j][r], 0.f) + EPS);
          }
        }
    } else {
      const bool isk = (region == 1);
      const int b = (int)(rowb >> 12);       // batch (256-row tile within batch)
      u16* dst = (isk ? kT : vT) + (long long)b * 1024 * 4096;
      const int nloc = (int)(rowb & 4095);
      #pragma unroll
      for (int j = 0; j < 4; ++j) {
        const int d = colb + j * 16 - region * 1024;
        float s = 0.f;
        #pragma unroll
        for (int i = 0; i < 8; ++i) {
          ushort4 pk;
          #pragma unroll
          for (int r = 0; r < 4; ++r) {
            float v = acc[i][j][r];
            if (isk) { v = fmaxf(v, 0.f) + EPS; s += v; }
            (&pk.x)[r] = f2b(v);
          }
          *(ushort4*)(dst + (long long)d * 4096 + nloc + i * 16) = pk;
        }
        if (isk) {
          s += __shfl_xor(s, 16);            // reduce 4 quads -> 128 n-rows/wave
          s += __shfl_xor(s, 32);
          if (quad == 0) atomicAdd(&ksum[b * 1024 + d], s);
        }
      }
    }
  } else if (MODE == 2) {
    float* out = (float*)Cv + (long long)bz * sC;
    #pragma unroll
    for (int i = 0; i < 8; ++i)
      #pragma unroll
      for (int j = 0; j < 4; ++j) {
        const int col = colb + j * 16;
        const float bj = bias[col];
        #pragma unroll
        for (int r = 0; r < 4; ++r) {
          const long long row = rowb + i * 16 + r;
          out[row * ldc + col] = acc[i][j][r] * zvec[(long long)bz * M + row] + bj;
        }
      }
  } else if (MODE == 3) {
    float* out = (float*)Cv + (long long)bz * sC;
    #pragma unroll
    for (int i = 0; i < 8; ++i)
      #pragma unroll
      for (int j = 0; j < 4; ++j) {
        const int col = colb + j * 16;
        #pragma unroll
        for (int r = 0; r < 4; ++r) {
          const long long row = rowb + i * 16 + r;
          out[row * ldc + col] = acc[i][j][r];
        }
      }
  } else {
    u16* out = (u16*)Cv + (long long)bz * sC;
    #pragma unroll
    for (int i = 0; i < 8; ++i)
      #pragma unroll
      for (int j = 0; j < 4; ++j) {
        const int col = colb + j * 16;
        #pragma unroll
        for (int r = 0; r < 4; ++r) {
          const long long row = rowb + i * 16 + r;
          out[row * ldc + col] = f2b(acc[i][j][r]);
        }
      }
  }
}

// ---------------------------------------------------------------------------
// 128^2-tile kernel (m97 structure) — kept for GEMM2b (small, K=1024).
// C = A * B^T.  MODE 1: bf16 out, plain.
// ---------------------------------------------------------------------------
template<int MODE>
__global__ __launch_bounds__(256) void gemm_abT(
    const u16* __restrict__ A, const u16* __restrict__ B, void* __restrict__ Cv,
    int M, int N, int K, int lda, int ldb, int ldc,
    long long sA, long long sB, long long sC,
    const float* __restrict__ zvec, const float* __restrict__ bias,
    u16* __restrict__ kT, u16* __restrict__ vT, float* __restrict__ ksum)
{
  __shared__ u16 lA[128 * 32];
  __shared__ u16 lB[128 * 32];
  const int tid  = threadIdx.x;
  const int wave = tid >> 6, lane = tid & 63;
  const int TN = gridDim.y;
  const int lin = blockIdx.x + gridDim.x * blockIdx.y;
  const int xcd = lin & 7, g = lin >> 3;
  const int bm = (g / TN) * 8 + xcd;
  const int bn = g % TN;
  const int bz = blockIdx.z;
  const u16* Ab = A + (long long)bz * sA;
  const u16* Bb = B + (long long)bz * sB;

  const int c0 = wave * 64 + lane;
  const int c1 = 256 + c0;
  const u16* gA0 = Ab + (long long)(bm * 128 + (c0 >> 2)) * lda + (c0 & 3) * 8;
  const u16* gA1 = Ab + (long long)(bm * 128 + (c1 >> 2)) * lda + (c1 & 3) * 8;
  const u16* gB0 = Bb + (long long)(bn * 128 + (c0 >> 2)) * ldb + (c0 & 3) * 8;
  const u16* gB1 = Bb + (long long)(bn * 128 + (c1 >> 2)) * ldb + (c1 & 3) * 8;
  u16* lA0 = &lA[(wave * 64) * 8];
  u16* lA1 = &lA[(256 + wave * 64) * 8];
  u16* lB0 = &lB[(wave * 64) * 8];
  u16* lB1 = &lB[(256 + wave * 64) * 8];

  const int wm = (wave & 1) * 64, wn = (wave >> 1) * 64;
  const int aoff = (wm + (lane & 15)) * 32 + (lane >> 4) * 8;
  const int boff = (wn + (lane & 15)) * 32 + (lane >> 4) * 8;

  f32x4 acc[4][4];
  #pragma unroll
  for (int i = 0; i < 4; i++)
    #pragma unroll
    for (int j = 0; j < 4; j++) acc[i][j] = f32x4{0.f, 0.f, 0.f, 0.f};

  for (int k0 = 0; k0 < K; k0 += 32) {
    load16_to_lds(gA0 + k0, lA0);
    load16_to_lds(gA1 + k0, lA1);
    load16_to_lds(gB0 + k0, lB0);
    load16_to_lds(gB1 + k0, lB1);
    __syncthreads();
    bf16x8 af[4], bfv[4];
    #pragma unroll
    for (int i = 0; i < 4; i++) af[i]  = *(const bf16x8*)&lA[aoff + i * 16 * 32];
    #pragma unroll
    for (int j = 0; j < 4; j++) bfv[j] = *(const bf16x8*)&lB[boff + j * 16 * 32];
    #pragma unroll
    for (int i = 0; i < 4; i++)
      #pragma unroll
      for (int j = 0; j < 4; j++)
        acc[i][j] = MFMA16(af[i], bfv[j], acc[i][j]);
    __syncthreads();
  }

  const int quad = lane >> 4, lc = lane & 15;
  const int rowb = bm * 128 + wm + quad * 4;
  const int colb = bn * 128 + wn + lc;

  #pragma unroll
  for (int i = 0; i < 4; i++) {
    #pragma unroll
    for (int j = 0; j < 4; j++) {
      const int col = colb + j * 16;
      float bj = 0.f;
      if (MODE == 2) bj = bias[col];
      #pragma unroll
      for (int r = 0; r < 4; r++) {
        const int row = rowb + i * 16 + r;
        float v = acc[i][j][r];
        if (MODE == 1) {
          ((u16*)Cv + (long long)bz * sC)[(long long)row * ldc + col] = f2b(v);
        } else if (MODE == 2) {
          float zz = zvec[(long long)bz * M + row];
          ((float*)Cv + (long long)bz * sC)[(long long)row * ldc + col] = v * zz + bj;
        }
      }
    }
  }
  (void)kT; (void)vT; (void)ksum;
}

// fp32 -> bf16 bulk convert (vectorized, grid-stride)
__global__ void cvt_f32_bf16(const float* __restrict__ s, u16* __restrict__ d, int n4) {
  int i = blockIdx.x * blockDim.x + threadIdx.x;
  int st = gridDim.x * blockDim.x;
  for (; i < n4; i += st) {
    float4 f = ((const float4*)s)[i];
    uint2 o;
    o.x = (unsigned)f2b(f.x) | ((unsigned)f2b(f.y) << 16);
    o.y = (unsigned)f2b(f.z) | ((unsigned)f2b(f.w) << 16);
    ((uint2*)d)[i] = o;
  }
}

__global__ void zero_f32(float* __restrict__ p, int n) {
  int i = blockIdx.x * blockDim.x + threadIdx.x;
  if (i < n) p[i] = 0.f;
}

// kv[b][i] = bf16(p[b][i] + p[8+b][i]); p = [16][1M] f32 partials, kv bf16 8M.
__global__ void reduce_kv(const float* __restrict__ p, u16* __restrict__ kv) {
  long long idx = blockIdx.x * blockDim.x + threadIdx.x;   // float4 units
  const long long st = (long long)gridDim.x * blockDim.x;
  for (; idx < 2097152; idx += st) {                        // 8M f32 / 4
    const long long b = idx >> 18;                          // 256K float4/batch
    const long long i = idx & 262143;
    float4 x = ((const float4*)p)[b * 262144 + i];
    float4 y = ((const float4*)p)[(8 + b) * 262144 + i];
    float4 s;
    s.x = x.x + y.x; s.y = x.y + y.y; s.z = x.z + y.z; s.w = x.w + y.w;
    uint2 o;
    o.x = (unsigned)f2b(s.x) | ((unsigned)f2b(s.y) << 16);
    o.y = (unsigned)f2b(s.z) | ((unsigned)f2b(s.w) << 16);
    ((uint2*)kv)[b * 262144 + i] = o;
  }
}

// z[row] = 1/(q[row,:]·ksum[b,:] + eps); one wave per row; q is [32768][1024]
__global__ void z_kernel(const u16* __restrict__ qbuf, const float* __restrict__ ksum,
                         float* __restrict__ z) {
  const int row  = blockIdx.x * 4 + (threadIdx.x >> 6);
  const int lane = threadIdx.x & 63;
  const int b = row >> 12;
  const uint4* q = (const uint4*)(qbuf + (long long)row * 1024);
  const float* ks = ksum + b * 1024;
  float s = 0.f;
  #pragma unroll
  for (int c = 0; c < 2; c++) {
    int idx = lane + c * 64;
    uint4 d = q[idx];
    unsigned w[4] = {d.x, d.y, d.z, d.w};
    const float* kk = ks + idx * 8;
    #pragma unroll
    for (int qq = 0; qq < 4; qq++)
      s += b2f((u16)(w[qq] & 0xFFFF)) * kk[qq * 2]
         + b2f((u16)(w[qq] >> 16))    * kk[qq * 2 + 1];
  }
  #pragma unroll
  for (int o = 32; o > 0; o >>= 1) s += __shfl_down(s, o);
  if (lane == 0) z[row] = 1.0f / (s + EPS);
}

extern "C" void kernel_launch(void* const* d_in, const int* in_sizes, int n_in,
                              void* d_out, int out_size, void* d_ws, size_t ws_size,
                              hipStream_t stream) {
  const float* x    = (const float*)d_in[0];   // [8,4096,1024]
  const float* Wqkv = (const float*)d_in[1];   // [3072,1024]
  const float* Wout = (const float*)d_in[2];   // [1024,1024]
  const float* bout = (const float*)d_in[3];   // [1024]

  char* ws = (char*)d_ws;                      // ~310.6 MiB
  u16* x_bf    = (u16*)(ws + 0);               // 64 MiB (dead after GEMM1 -> f32 partials)
  u16* qbuf    = (u16*)(ws + 67108864);        // 64 MiB [32768][1024]
  u16* kT      = (u16*)(ws + 134217728);       // 64 MiB [8][1024][4096]
  u16* vT      = (u16*)(ws + 201326592);       // 64 MiB [8][1024][4096]
  u16* wqkv_bf = (u16*)(ws + 268435456);       // 6 MiB
  u16* wout_bf = (u16*)(ws + 274726912);       // 2 MiB
  u16* kv      = (u16*)(ws + 276824064);       // 16 MiB [8][1024][1024]
  u16* kvwT    = (u16*)(ws + 293601280);       // 16 MiB [8][1024][1024]
  float* ksum  = (float*)(ws + 310378496);     // 32 KiB [8][1024]
  float* z     = (float*)(ws + 310411264);     // 128 KiB [32768]

  cvt_f32_bf16<<<4096, 256, 0, stream>>>(x,    x_bf,    33554432 / 4);
  cvt_f32_bf16<<<1024, 256, 0, stream>>>(Wqkv, wqkv_bf,  3145728 / 4);
  cvt_f32_bf16<<<512,  256, 0, stream>>>(Wout, wout_bf,  1048576 / 4);
  zero_f32<<<32, 256, 0, stream>>>(ksum, 8192);

  // GEMM1 (256^2, 3-barrier race-free schedule): x @ Wqkv^T -> q + kT/vT + ksum
  gemm256<0><<<dim3(128, 12, 1), 512, 0, stream>>>(
      x_bf, wqkv_bf, qbuf, 32768, 3072, 1024, 1024, 1024, 1024,
      0, 0, 0, nullptr, nullptr, kT, vT, ksum);

  // z = 1/(q·ksum + eps)
  z_kernel<<<8192, 256, 0, stream>>>(qbuf, ksum, z);

  // GEMM2 (split-K=2 on gemm256): partial[kh*8+b] = kT_b[:,kh] @ vT_b[:,kh]^T
  gemm256<3><<<dim3(4, 4, 16), 512, 0, stream>>>(
      kT, vT, (float*)x_bf, 1024, 1024, 2048, 4096, 4096, 1024,
      4194304, 4194304, 1048576, nullptr, nullptr, nullptr, nullptr, nullptr);

  // kv = bf16(partial[b] + partial[8+b])
  reduce_kv<<<2048, 256, 0, stream>>>((const float*)x_bf, kv);

  // GEMM2b (batched 8): kvwT[f][d] = Wout @ kv_b^T  (K=1024)
  gemm_abT<1><<<dim3(8, 8, 8), 256, 0, stream>>>(
      wout_bf, kv, kvwT, 1024, 1024, 1024, 1024, 1024, 1024,
      0, 1048576, 1048576, nullptr, nullptr, nullptr, nullptr, nullptr);

  // GEMM3 (256^2, 3-barrier race-free schedule, batched 8)
  gemm256<2><<<dim3(16, 4, 8), 512, 0, stream>>>(
      qbuf, kvwT, d_out, 4096, 1024, 1024, 1024, 1024, 1024,
      4194304, 1048576, 4194304, z, bout, nullptr, nullptr, nullptr);
}

// Round 8
// 667.193 us; speedup vs baseline: 1.1481x; 1.0227x over previous
//
#include <hip/hip_runtime.h>

// LinearAttention on MI355X (gfx950), bf16 MFMA pipeline.
// R9: K-loop restored to R1's verbatim 8-barrier schedule (best measured:
// GEMM1 246-249 µs; R5/R8 schedule experiments both regressed). NEW: MODE-0
// kv-epilogue stores via LDS transpose — old path wrote 64x8B at 8KB stride
// per instruction (64 L2 transactions/instr, ~16K/block); new path stages the
// 256x256 tile in LDS ([128 d][264 n], +8 pad = 2-way-free) in two passes and
// stores 512B-contiguous d-rows (256 instrs/block). ksum from acc pre-reuse.
// shA/shB unioned into one smem block, reused after the K-loop's final barrier.

#define EPS 1e-6f

using u16 = unsigned short;
typedef __attribute__((ext_vector_type(4))) float f32x4;
typedef __attribute__((ext_vector_type(8))) __bf16 bf16x8;

__device__ __forceinline__ u16 f2b(float f) {
  unsigned u = __builtin_bit_cast(unsigned, f);
  u += 0x7FFFu + ((u >> 16) & 1u);     // RNE
  return (u16)(u >> 16);
}
__device__ __forceinline__ float b2f(u16 h) {
  return __builtin_bit_cast(float, (unsigned)h << 16);
}

typedef const __attribute__((address_space(1))) void* gas1_t;
typedef __attribute__((address_space(3))) void* las3_t;

__device__ __forceinline__ void load16_to_lds(const void* g, void* l) {
  __builtin_amdgcn_global_load_lds((gas1_t)g, (las3_t)l, 16, 0, 0);
}

#define BARRIER() do { asm volatile("" ::: "memory"); __builtin_amdgcn_s_barrier(); asm volatile("" ::: "memory"); } while (0)
#define WAITL0()  asm volatile("s_waitcnt lgkmcnt(0)" ::: "memory")
#define WAITV(n)  asm volatile("s_waitcnt vmcnt(" #n ")" ::: "memory")
#define MFMA16(a, b, c) __builtin_amdgcn_mfma_f32_16x16x32_bf16((a), (b), (c), 0, 0, 0)

// Stage one 128x64 half-tile: LDS dest linear (global_load_lds requirement),
// global source column pre-swizzled with the involution chunk ^= (row&7) so the
// swizzled ds_read side reads the right bytes (rule: both-sides-or-neither).
__device__ __forceinline__ void stage_half(const u16* g, int ld, u16* l,
                                           int r0, int csw, int woff) {
  load16_to_lds(g + (long long)r0 * ld + csw, l + woff);
  load16_to_lds(g + (long long)(r0 + 64) * ld + csw, l + 4096 + woff);
}

// ---------------------------------------------------------------------------
// 256x256-tile, BK=64, 8 waves (2M x 4N), double-buffered 128 KiB LDS,
// 4 phases per K-tile, counted vmcnt(6) — R1-verified schedule.
// MODE 0: GEMM1 fused epilogue (q n-major relu+eps / kT,vT LDS-transposed /
//         ksum). MODE 2: f32 out, v*z[row] + bias[col].
// MODE 3: split-K partial, f32 plain out; bz = {batch=bz&7, kh=bz>>3}.
// Requires M%256==0, N%256==0, K%64==0; XCD swizzle only when gridDim.x>=8.
// ---------------------------------------------------------------------------
template<int MODE>
__global__ __launch_bounds__(512, 2) void gemm256(
    const u16* __restrict__ A, const u16* __restrict__ B, void* __restrict__ Cv,
    int M, int N, int K, int lda, int ldb, int ldc,
    long long sA, long long sB, long long sC,
    const float* __restrict__ zvec, const float* __restrict__ bias,
    u16* __restrict__ kT, u16* __restrict__ vT, float* __restrict__ ksum)
{
  __shared__ __align__(16) u16 smem[65536];   // 128 KiB: shA = [0,32768), shB = [32768,65536)
  u16* shA = smem;
  u16* shB = smem + 32768;

  const int tid  = threadIdx.x;
  const int lane = tid & 63, wave = tid >> 6;
  const int wr = wave >> 2, wc = wave & 3;           // 2M x 4N wave grid
  const int quad = lane >> 4, lc = lane & 15;

  // XCD-aware swizzle (bijective when grid multiple of 8); identity for small grids
  const int TN = gridDim.y;
  const int lin = blockIdx.x + gridDim.x * blockIdx.y;
  int bm, bn;
  if (gridDim.x >= 8) {
    const int xcd = lin & 7, g = lin >> 3;
    bm = (g / TN) * 8 + xcd;
    bn = g % TN;
  } else {
    bm = blockIdx.x;
    bn = blockIdx.y;
  }
  const int bz = blockIdx.z;
  const u16* Ab;
  const u16* Bb;
  if (MODE == 3) {
    const int bb = bz & 7, kh = bz >> 3;
    Ab = A + (long long)bb * sA + kh * 2048;
    Bb = B + (long long)bb * sB + kh * 2048;
  } else {
    Ab = A + (long long)bz * sA;
    Bb = B + (long long)bz * sB;
  }

  // staging addressing: thread covers chunks {tid, 512+tid} of each half-tile
  const int r0   = tid >> 3;                                   // rows 0..63 (+64)
  const int csw  = (((tid & 7) ^ ((tid >> 3) & 7)) << 3);      // inverse-swz col
  const int woff = wave * 512;                                 // wave-uniform LDS off

  // fragment read addressing (swizzled chunk index, constant per lane)
  const int ch0 = ((quad ^ (lane & 7)) << 3);                  // ksub 0
  const int ch1 = (((4 + quad) ^ (lane & 7)) << 3);            // ksub 1
  const int aRow = wr * 128 + lc;
  const int bRow = wc * 64 + lc;

  const int NT = K >> 6;

  f32x4 acc[8][4];
  #pragma unroll
  for (int i = 0; i < 8; ++i)
    #pragma unroll
    for (int j = 0; j < 4; ++j) acc[i][j] = f32x4{0.f, 0.f, 0.f, 0.f};

  auto stA = [&](int h, int t) {
    stage_half(Ab + ((long long)bm * 256 + h * 128) * lda + t * 64, lda,
               shA + (t & 1) * 16384 + h * 8192, r0, csw, woff);
  };
  auto stB = [&](int h, int t) {
    stage_half(Bb + ((long long)bn * 256 + h * 128) * ldb + t * 64, ldb,
               shB + (t & 1) * 16384 + h * 8192, r0, csw, woff);
  };

  // prologue: tile0 fully + tile1 {A0,A1,B0}; keep tile1's 3 halves in flight
  stA(0, 0); stA(1, 0); stB(0, 0); stB(1, 0);
  if (NT > 1) { stA(0, 1); stA(1, 1); stB(0, 1); WAITV(6); }
  else        { WAITV(0); }
  BARRIER();

  for (int t = 0; t < NT; ++t) {
    const u16* aB = shA + (t & 1) * 16384;
    const u16* bB = shB + (t & 1) * 16384;
    bf16x8 aF[4][2], b01[2][2], b23[2][2];

    // ---- phase 1: read A[i0-3]+B[j0-1]; stage B1(t+1) [other buf]; mfma (0,0)
    #pragma unroll
    for (int i = 0; i < 4; ++i) {
      aF[i][0] = *(const bf16x8*)&aB[(aRow + i * 16) * 64 + ch0];
      aF[i][1] = *(const bf16x8*)&aB[(aRow + i * 16) * 64 + ch1];
    }
    #pragma unroll
    for (int j = 0; j < 2; ++j) {
      b01[j][0] = *(const bf16x8*)&bB[(bRow + j * 16) * 64 + ch0];
      b01[j][1] = *(const bf16x8*)&bB[(bRow + j * 16) * 64 + ch1];
    }
    if (t + 1 < NT) stB(1, t + 1);
    BARRIER(); WAITL0();
    __builtin_amdgcn_s_setprio(1);
    #pragma unroll
    for (int i = 0; i < 4; ++i)
      #pragma unroll
      for (int j = 0; j < 2; ++j) {
        acc[i][j] = MFMA16(aF[i][0], b01[j][0], acc[i][j]);
        acc[i][j] = MFMA16(aF[i][1], b01[j][1], acc[i][j]);
      }
    __builtin_amdgcn_s_setprio(0);
    BARRIER();

    // ---- phase 2: read B[j2-3]; mfma (0,1)
    #pragma unroll
    for (int j = 0; j < 2; ++j) {
      b23[j][0] = *(const bf16x8*)&bB[(bRow + (2 + j) * 16) * 64 + ch0];
      b23[j][1] = *(const bf16x8*)&bB[(bRow + (2 + j) * 16) * 64 + ch1];
    }
    BARRIER(); WAITL0();
    __builtin_amdgcn_s_setprio(1);
    #pragma unroll
    for (int i = 0; i < 4; ++i)
      #pragma unroll
      for (int j = 0; j < 2; ++j) {
        acc[i][2 + j] = MFMA16(aF[i][0], b23[j][0], acc[i][2 + j]);
        acc[i][2 + j] = MFMA16(aF[i][1], b23[j][1], acc[i][2 + j]);
      }
    __builtin_amdgcn_s_setprio(0);
    BARRIER();

    // ---- phase 3: read A[i4-7]; B region dead -> stage B0(t+2); mfma (1,0)
    #pragma unroll
    for (int i = 0; i < 4; ++i) {
      aF[i][0] = *(const bf16x8*)&aB[(aRow + (4 + i) * 16) * 64 + ch0];
      aF[i][1] = *(const bf16x8*)&aB[(aRow + (4 + i) * 16) * 64 + ch1];
    }
    if (t + 2 < NT) stB(0, t + 2);
    BARRIER(); WAITL0();
    __builtin_amdgcn_s_setprio(1);
    #pragma unroll
    for (int i = 0; i < 4; ++i)
      #pragma unroll
      for (int j = 0; j < 2; ++j) {
        acc[4 + i][j] = MFMA16(aF[i][0], b01[j][0], acc[4 + i][j]);
        acc[4 + i][j] = MFMA16(aF[i][1], b01[j][1], acc[4 + i][j]);
      }
    __builtin_amdgcn_s_setprio(0);
    BARRIER();

    // ---- phase 4: A region dead -> stage A0,A1(t+2); mfma (1,1); vmcnt(6)
    if (t + 2 < NT) { stA(0, t + 2); stA(1, t + 2); }
    BARRIER(); WAITL0();
    __builtin_amdgcn_s_setprio(1);
    #pragma unroll
    for (int i = 0; i < 4; ++i)
      #pragma unroll
      for (int j = 0; j < 2; ++j) {
        acc[4 + i][2 + j] = MFMA16(aF[i][0], b23[j][0], acc[4 + i][2 + j]);
        acc[4 + i][2 + j] = MFMA16(aF[i][1], b23[j][1], acc[4 + i][2 + j]);
      }
    __builtin_amdgcn_s_setprio(0);
    if (t + 2 < NT) { WAITV(6); } else { WAITV(0); }
    BARRIER();
  }

  // ---- epilogue.  C/D layout (m89): col = lane&15, row = (lane>>4)*4 + reg
  const long long rowb = (long long)bm * 256 + wr * 128 + quad * 4;
  const int colb = bn * 256 + wc * 64 + lc;

  if (MODE == 0) {
    const int region = bn >> 2;              // blocks are region-uniform (256|1024)
    if (region == 0) {
      u16* q = (u16*)Cv;
      #pragma unroll
      for (int i = 0; i < 8; ++i)
        #pragma unroll
        for (int j = 0; j < 4; ++j) {
          const int col = colb + j * 16;
          #pragma unroll
          for (int r = 0; r < 4; ++r) {
            const long long row = rowb + i * 16 + r;
            q[row * ldc + col] = f2b(fmaxf(acc[i][j][r], 0.f) + EPS);
          }
        }
    } else {
      const bool isk = (region == 1);
      const int b = bm >> 4;                 // batch (16 M-blocks per batch)
      const int nb = (bm & 15) * 256;        // block n-base within batch
      const int dbase = (bn - (isk ? 4 : 8)) * 256;
      u16* dst = (isk ? kT : vT) + (long long)b * 1024 * 4096;

      // 1) ksum from acc (k-region only), before smem reuse
      if (isk) {
        #pragma unroll
        for (int j = 0; j < 4; ++j) {
          float s = 0.f;
          #pragma unroll
          for (int i = 0; i < 8; ++i)
            #pragma unroll
            for (int r = 0; r < 4; ++r) s += fmaxf(acc[i][j][r], 0.f) + EPS;
          s += __shfl_xor(s, 16);            // reduce quads -> 256 n-rows
          s += __shfl_xor(s, 32);
          if (quad == 0) {
            const int d = dbase + wc * 64 + j * 16 + lc;
            atomicAdd(&ksum[b * 1024 + d], s);
          }
        }
      }

      // 2) LDS transpose in two 128-d passes: T = [128 d][264 n] (pad 8)
      u16* T = smem;
      const int nloc = wr * 128 + quad * 4;
      #pragma unroll
      for (int p = 0; p < 2; ++p) {
        if ((wc >> 1) == p) {                // waves owning d < / >= 128 write
          #pragma unroll
          for (int j = 0; j < 4; ++j) {
            const int dd = (wc & 1) * 64 + j * 16 + lc;
            #pragma unroll
            for (int i = 0; i < 8; ++i) {
              ushort4 pk;
              #pragma unroll
              for (int r = 0; r < 4; ++r) {
                float v = acc[i][j][r];
                if (isk) v = fmaxf(v, 0.f) + EPS;
                (&pk.x)[r] = f2b(v);
              }
              *(ushort4*)&T[dd * 264 + nloc + i * 16] = pk;
            }
          }
        }
        BARRIER();
        // all 8 waves store 16 d-rows each: 512B contiguous per instruction
        #pragma unroll
        for (int ii = 0; ii < 16; ++ii) {
          const int dd = wave * 16 + ii;
          ushort4 v = *(const ushort4*)&T[dd * 264 + lane * 4];
          *(ushort4*)(dst + (long long)(dbase + p * 128 + dd) * 4096 + nb + lane * 4) = v;
        }
        BARRIER();
      }
    }
  } else if (MODE == 2) {
    float* out = (float*)Cv + (long long)bz * sC;
    #pragma unroll
    for (int i = 0; i < 8; ++i)
      #pragma unroll
      for (int j = 0; j < 4; ++j) {
        const int col = colb + j * 16;
        const float bj = bias[col];
        #pragma unroll
        for (int r = 0; r < 4; ++r) {
          const long long row = rowb + i * 16 + r;
          out[row * ldc + col] = acc[i][j][r] * zvec[(long long)bz * M + row] + bj;
        }
      }
  } else if (MODE == 3) {
    float* out = (float*)Cv + (long long)bz * sC;
    #pragma unroll
    for (int i = 0; i < 8; ++i)
      #pragma unroll
      for (int j = 0; j < 4; ++j) {
        const int col = colb + j * 16;
        #pragma unroll
        for (int r = 0; r < 4; ++r) {
          const long long row = rowb + i * 16 + r;
          out[row * ldc + col] = acc[i][j][r];
        }
      }
  } else {
    u16* out = (u16*)Cv + (long long)bz * sC;
    #pragma unroll
    for (int i = 0; i < 8; ++i)
      #pragma unroll
      for (int j = 0; j < 4; ++j) {
        const int col = colb + j * 16;
        #pragma unroll
        for (int r = 0; r < 4; ++r) {
          const long long row = rowb + i * 16 + r;
          out[row * ldc + col] = f2b(acc[i][j][r]);
        }
      }
  }
}

// ---------------------------------------------------------------------------
// 128^2-tile kernel (m97 structure) — kept for GEMM2b (small, K=1024).
// ---------------------------------------------------------------------------
template<int MODE>
__global__ __launch_bounds__(256) void gemm_abT(
    const u16* __restrict__ A, const u16* __restrict__ B, void* __restrict__ Cv,
    int M, int N, int K, int lda, int ldb, int ldc,
    long long sA, long long sB, long long sC,
    const float* __restrict__ zvec, const float* __restrict__ bias,
    u16* __restrict__ kT, u16* __restrict__ vT, float* __restrict__ ksum)
{
  __shared__ u16 lA[128 * 32];
  __shared__ u16 lB[128 * 32];
  const int tid  = threadIdx.x;
  const int wave = tid >> 6, lane = tid & 63;
  const int TN = gridDim.y;
  const int lin = blockIdx.x + gridDim.x * blockIdx.y;
  const int xcd = lin & 7, g = lin >> 3;
  const int bm = (g / TN) * 8 + xcd;
  const int bn = g % TN;
  const int bz = blockIdx.z;
  const u16* Ab = A + (long long)bz * sA;
  const u16* Bb = B + (long long)bz * sB;

  const int c0 = wave * 64 + lane;
  const int c1 = 256 + c0;
  const u16* gA0 = Ab + (long long)(bm * 128 + (c0 >> 2)) * lda + (c0 & 3) * 8;
  const u16* gA1 = Ab + (long long)(bm * 128 + (c1 >> 2)) * lda + (c1 & 3) * 8;
  const u16* gB0 = Bb + (long long)(bn * 128 + (c0 >> 2)) * ldb + (c0 & 3) * 8;
  const u16* gB1 = Bb + (long long)(bn * 128 + (c1 >> 2)) * ldb + (c1 & 3) * 8;
  u16* lA0 = &lA[(wave * 64) * 8];
  u16* lA1 = &lA[(256 + wave * 64) * 8];
  u16* lB0 = &lB[(wave * 64) * 8];
  u16* lB1 = &lB[(256 + wave * 64) * 8];

  const int wm = (wave & 1) * 64, wn = (wave >> 1) * 64;
  const int aoff = (wm + (lane & 15)) * 32 + (lane >> 4) * 8;
  const int boff = (wn + (lane & 15)) * 32 + (lane >> 4) * 8;

  f32x4 acc[4][4];
  #pragma unroll
  for (int i = 0; i < 4; i++)
    #pragma unroll
    for (int j = 0; j < 4; j++) acc[i][j] = f32x4{0.f, 0.f, 0.f, 0.f};

  for (int k0 = 0; k0 < K; k0 += 32) {
    load16_to_lds(gA0 + k0, lA0);
    load16_to_lds(gA1 + k0, lA1);
    load16_to_lds(gB0 + k0, lB0);
    load16_to_lds(gB1 + k0, lB1);
    __syncthreads();
    bf16x8 af[4], bfv[4];
    #pragma unroll
    for (int i = 0; i < 4; i++) af[i]  = *(const bf16x8*)&lA[aoff + i * 16 * 32];
    #pragma unroll
    for (int j = 0; j < 4; j++) bfv[j] = *(const bf16x8*)&lB[boff + j * 16 * 32];
    #pragma unroll
    for (int i = 0; i < 4; i++)
      #pragma unroll
      for (int j = 0; j < 4; j++)
        acc[i][j] = MFMA16(af[i], bfv[j], acc[i][j]);
    __syncthreads();
  }

  const int quad = lane >> 4, lc = lane & 15;
  const int rowb = bm * 128 + wm + quad * 4;
  const int colb = bn * 128 + wn + lc;

  #pragma unroll
  for (int i = 0; i < 4; i++) {
    #pragma unroll
    for (int j = 0; j < 4; j++) {
      const int col = colb + j * 16;
      float bj = 0.f;
      if (MODE == 2) bj = bias[col];
      #pragma unroll
      for (int r = 0; r < 4; r++) {
        const int row = rowb + i * 16 + r;
        float v = acc[i][j][r];
        if (MODE == 1) {
          ((u16*)Cv + (long long)bz * sC)[(long long)row * ldc + col] = f2b(v);
        } else if (MODE == 2) {
          float zz = zvec[(long long)bz * M + row];
          ((float*)Cv + (long long)bz * sC)[(long long)row * ldc + col] = v * zz + bj;
        }
      }
    }
  }
  (void)kT; (void)vT; (void)ksum;
}

// fp32 -> bf16 bulk convert (vectorized, grid-stride)
__global__ void cvt_f32_bf16(const float* __restrict__ s, u16* __restrict__ d, int n4) {
  int i = blockIdx.x * blockDim.x + threadIdx.x;
  int st = gridDim.x * blockDim.x;
  for (; i < n4; i += st) {
    float4 f = ((const float4*)s)[i];
    uint2 o;
    o.x = (unsigned)f2b(f.x) | ((unsigned)f2b(f.y) << 16);
    o.y = (unsigned)f2b(f.z) | ((unsigned)f2b(f.w) << 16);
    ((uint2*)d)[i] = o;
  }
}

__global__ void zero_f32(float* __restrict__ p, int n) {
  int i = blockIdx.x * blockDim.x + threadIdx.x;
  if (i < n) p[i] = 0.f;
}

// kv[b][i] = bf16(p[b][i] + p[8+b][i]); p = [16][1M] f32 partials, kv bf16 8M.
__global__ void reduce_kv(const float* __restrict__ p, u16* __restrict__ kv) {
  long long idx = blockIdx.x * blockDim.x + threadIdx.x;   // float4 units
  const long long st = (long long)gridDim.x * blockDim.x;
  for (; idx < 2097152; idx += st) {                        // 8M f32 / 4
    const long long b = idx >> 18;                          // 256K float4/batch
    const long long i = idx & 262143;
    float4 x = ((const float4*)p)[b * 262144 + i];
    float4 y = ((const float4*)p)[(8 + b) * 262144 + i];
    float4 s;
    s.x = x.x + y.x; s.y = x.y + y.y; s.z = x.z + y.z; s.w = x.w + y.w;
    uint2 o;
    o.x = (unsigned)f2b(s.x) | ((unsigned)f2b(s.y) << 16);
    o.y = (unsigned)f2b(s.z) | ((unsigned)f2b(s.w) << 16);
    ((uint2*)kv)[b * 262144 + i] = o;
  }
}

// z[row] = 1/(q[row,:]·ksum[b,:] + eps); one wave per row; q is [32768][1024]
__global__ void z_kernel(const u16* __restrict__ qbuf, const float* __restrict__ ksum,
                         float* __restrict__ z) {
  const int row  = blockIdx.x * 4 + (threadIdx.x >> 6);
  const int lane = threadIdx.x & 63;
  const int b = row >> 12;
  const uint4* q = (const uint4*)(qbuf + (long long)row * 1024);
  const float* ks = ksum + b * 1024;
  float s = 0.f;
  #pragma unroll
  for (int c = 0; c < 2; c++) {
    int idx = lane + c * 64;
    uint4 d = q[idx];
    unsigned w[4] = {d.x, d.y, d.z, d.w};
    const float* kk = ks + idx * 8;
    #pragma unroll
    for (int qq = 0; qq < 4; qq++)
      s += b2f((u16)(w[qq] & 0xFFFF)) * kk[qq * 2]
         + b2f((u16)(w[qq] >> 16))    * kk[qq * 2 + 1];
  }
  #pragma unroll
  for (int o = 32; o > 0; o >>= 1) s += __shfl_down(s, o);
  if (lane == 0) z[row] = 1.0f / (s + EPS);
}

extern "C" void kernel_launch(void* const* d_in, const int* in_sizes, int n_in,
                              void* d_out, int out_size, void* d_ws, size_t ws_size,
                              hipStream_t stream) {
  const float* x    = (const float*)d_in[0];   // [8,4096,1024]
  const float* Wqkv = (const float*)d_in[1];   // [3072,1024]
  const float* Wout = (const float*)d_in[2];   // [1024,1024]
  const float* bout = (const float*)d_in[3];   // [1024]

  char* ws = (char*)d_ws;                      // ~310.6 MiB
  u16* x_bf    = (u16*)(ws + 0);               // 64 MiB (dead after GEMM1 -> f32 partials)
  u16* qbuf    = (u16*)(ws + 67108864);        // 64 MiB [32768][1024]
  u16* kT      = (u16*)(ws + 134217728);       // 64 MiB [8][1024][4096]
  u16* vT      = (u16*)(ws + 201326592);       // 64 MiB [8][1024][4096]
  u16* wqkv_bf = (u16*)(ws + 268435456);       // 6 MiB
  u16* wout_bf = (u16*)(ws + 274726912);       // 2 MiB
  u16* kv      = (u16*)(ws + 276824064);       // 16 MiB [8][1024][1024]
  u16* kvwT    = (u16*)(ws + 293601280);       // 16 MiB [8][1024][1024]
  float* ksum  = (float*)(ws + 310378496);     // 32 KiB [8][1024]
  float* z     = (float*)(ws + 310411264);     // 128 KiB [32768]

  cvt_f32_bf16<<<4096, 256, 0, stream>>>(x,    x_bf,    33554432 / 4);
  cvt_f32_bf16<<<1024, 256, 0, stream>>>(Wqkv, wqkv_bf,  3145728 / 4);
  cvt_f32_bf16<<<512,  256, 0, stream>>>(Wout, wout_bf,  1048576 / 4);
  zero_f32<<<32, 256, 0, stream>>>(ksum, 8192);

  // GEMM1 (256^2, R1 schedule + LDS-transposed kv stores)
  gemm256<0><<<dim3(128, 12, 1), 512, 0, stream>>>(
      x_bf, wqkv_bf, qbuf, 32768, 3072, 1024, 1024, 1024, 1024,
      0, 0, 0, nullptr, nullptr, kT, vT, ksum);

  // z = 1/(q·ksum + eps)
  z_kernel<<<8192, 256, 0, stream>>>(qbuf, ksum, z);

  // GEMM2 (split-K=2 on gemm256): partial[kh*8+b] = kT_b[:,kh] @ vT_b[:,kh]^T
  gemm256<3><<<dim3(4, 4, 16), 512, 0, stream>>>(
      kT, vT, (float*)x_bf, 1024, 1024, 2048, 4096, 4096, 1024,
      4194304, 4194304, 1048576, nullptr, nullptr, nullptr, nullptr, nullptr);

  // kv = bf16(partial[b] + partial[8+b])
  reduce_kv<<<2048, 256, 0, stream>>>((const float*)x_bf, kv);

  // GEMM2b (batched 8): kvwT[f][d] = Wout @ kv_b^T  (K=1024)
  gemm_abT<1><<<dim3(8, 8, 8), 256, 0, stream>>>(
      wout_bf, kv, kvwT, 1024, 1024, 1024, 1024, 1024, 1024,
      0, 1048576, 1048576, nullptr, nullptr, nullptr, nullptr, nullptr);

  // GEMM3 (256^2, R1 schedule, batched 8): out = z*(q@kvwT^T)+b_out
  gemm256<2><<<dim3(16, 4, 8), 512, 0, stream>>>(
      qbuf, kvwT, d_out, 4096, 1024, 1024, 1024, 1024, 1024,
      4194304, 1048576, 4194304, z, bout, nullptr, nullptr, nullptr);
}